// Round 1
// baseline (2375.010 us; speedup 1.0000x reference)
//
#include <hip/hip_runtime.h>
#include <hip/hip_bf16.h>

namespace {

constexpr int B  = 4;
constexpr int P0 = 196608, P1 = 49152, P2 = 12288;
constexpr int DEG = 8;
constexpr float EPS = 1e-5f;
constexpr int NCH = 96;           // colsum chunks per batch
constexpr int CHP = P2 / NCH;     // 128 pixels per chunk

// ---------------------------------------------------------------------------
// Sparse Chebyshev step: out[b,p,:] = alpha * sum_d vals[p,d]*in[b,cols[p,d],:]
//                                     + beta * prev[b,p,:]
// Vectorized float4 over channels (Cv = C/4).
// ---------------------------------------------------------------------------
__global__ __launch_bounds__(256)
void lmul_kernel(const float* __restrict__ in, const float* __restrict__ prev,
                 const int* __restrict__ cols, const float* __restrict__ vals,
                 float* __restrict__ out, int P, int Cv, float alpha, float beta)
{
    long idx = (long)blockIdx.x * blockDim.x + threadIdx.x;
    long total = (long)B * P * Cv;
    if (idx >= total) return;
    int v   = (int)(idx % Cv);
    long r  = idx / Cv;
    int p   = (int)(r % P);
    int b   = (int)(r / P);

    const float4* in4 = (const float4*)in;
    float4 acc = make_float4(0.f, 0.f, 0.f, 0.f);
#pragma unroll
    for (int d = 0; d < DEG; ++d) {
        int   col = cols[p * DEG + d];
        float w   = vals[p * DEG + d];
        float4 x  = in4[(size_t)(b * P + col) * Cv + v];
        acc.x = fmaf(w, x.x, acc.x);
        acc.y = fmaf(w, x.y, acc.y);
        acc.z = fmaf(w, x.z, acc.z);
        acc.w = fmaf(w, x.w, acc.w);
    }
    size_t o = (size_t)(b * P + p) * Cv + v;
    if (beta != 0.f) {
        float4 pv = ((const float4*)prev)[o];
        acc.x = fmaf(alpha, acc.x, beta * pv.x);
        acc.y = fmaf(alpha, acc.y, beta * pv.y);
        acc.z = fmaf(alpha, acc.z, beta * pv.z);
        acc.w = fmaf(alpha, acc.w, beta * pv.w);
    } else if (alpha != 1.f) {
        acc.x *= alpha; acc.y *= alpha; acc.z *= alpha; acc.w *= alpha;
    }
    ((float4*)out)[o] = acc;
}

// ---------------------------------------------------------------------------
// Fused: h = concat(t0..t3) @ W + bias ; LayerNorm ; ReLU ; optional 4:1 pool.
// Block: TH threads = PIXB pixels x (COUT/4) threads; each thread owns 4 couts
// of one pixel. x rows staged in padded LDS (broadcast reads); W streamed from
// global as float4 (coalesced, L1/L2 resident). LN via wave shuffles (pixel's
// thread-group is 16/32/64 contiguous lanes).
// ---------------------------------------------------------------------------
template <int CIN, int COUT, int POOL, int TH>
__global__ __launch_bounds__(TH)
void cheb_mm_ln_kernel(int P,
                       const float* __restrict__ t0, const float* __restrict__ t1,
                       const float* __restrict__ t2, const float* __restrict__ t3,
                       const float* __restrict__ W,  const float* __restrict__ bias,
                       const float* __restrict__ gam, const float* __restrict__ bet,
                       float* __restrict__ out)
{
    constexpr int KC   = 4 * CIN;
    constexpr int TPP  = COUT / 4;      // threads per pixel
    constexpr int PIXB = TH / TPP;      // pixels per block
    constexpr int LDK  = KC + 1;        // padded LDS stride (kills 4-way conflict)

    __shared__ float xs[PIXB * LDK];
    constexpr int HSZ = (POOL == 4) ? PIXB * COUT : 4;
    __shared__ float hs[HSZ];

    const int tid        = threadIdx.x;
    const int nblk_per_b = P / PIXB;
    const int b          = blockIdx.x / nblk_per_b;
    const int pg         = blockIdx.x % nblk_per_b;
    const int p0         = pg * PIXB;

    // stage xk rows into LDS: k = term*CIN + c
    const float* tp[4] = { t0, t1, t2, t3 };
#pragma unroll
    for (int term = 0; term < 4; ++term) {
        const float* __restrict__ src = tp[term];
        for (int i = tid; i < PIXB * CIN; i += TH) {
            int pix = i / CIN, c = i % CIN;
            xs[pix * LDK + term * CIN + c] =
                src[((size_t)(b * P + p0 + pix)) * CIN + c];
        }
    }
    __syncthreads();

    const int pix = tid / TPP;
    const int cq  = tid % TPP;
    const int c0  = cq * 4;

    float4 acc = *(const float4*)&bias[c0];
    const float* __restrict__ xrow = &xs[pix * LDK];
    const float* __restrict__ wp   = W + c0;
#pragma unroll 8
    for (int k = 0; k < KC; ++k) {
        float  xv = xrow[k];
        float4 w  = *(const float4*)wp;
        wp += COUT;
        acc.x = fmaf(xv, w.x, acc.x);
        acc.y = fmaf(xv, w.y, acc.y);
        acc.z = fmaf(xv, w.z, acc.z);
        acc.w = fmaf(xv, w.w, acc.w);
    }

    // LayerNorm over COUT (TPP contiguous lanes per pixel) + ReLU
    float s = acc.x + acc.y + acc.z + acc.w;
    float q = acc.x * acc.x + acc.y * acc.y + acc.z * acc.z + acc.w * acc.w;
#pragma unroll
    for (int m = 1; m < TPP; m <<= 1) {
        s += __shfl_xor(s, m, 64);
        q += __shfl_xor(q, m, 64);
    }
    float mu   = s * (1.f / COUT);
    float var  = q * (1.f / COUT) - mu * mu;
    float rstd = rsqrtf(var + EPS);
    float4 gv = *(const float4*)&gam[c0];
    float4 bv = *(const float4*)&bet[c0];
    float4 h;
    h.x = fmaxf(fmaf(gv.x * rstd, acc.x - mu, bv.x), 0.f);
    h.y = fmaxf(fmaf(gv.y * rstd, acc.y - mu, bv.y), 0.f);
    h.z = fmaxf(fmaf(gv.z * rstd, acc.z - mu, bv.z), 0.f);
    h.w = fmaxf(fmaf(gv.w * rstd, acc.w - mu, bv.w), 0.f);

    if constexpr (POOL == 4) {
        *(float4*)&hs[pix * COUT + c0] = h;
        __syncthreads();
        constexpr int OUTROWS = PIXB / 4;
        for (int i = tid; i < OUTROWS * COUT; i += TH) {
            int op = i / COUT, c = i % COUT;
            float v = 0.25f * (hs[(op * 4 + 0) * COUT + c] +
                               hs[(op * 4 + 1) * COUT + c] +
                               hs[(op * 4 + 2) * COUT + c] +
                               hs[(op * 4 + 3) * COUT + c]);
            out[((size_t)(b * (P / 4) + p0 / 4 + op)) * COUT + c] = v;
        }
    } else {
        *(float4*)&out[((size_t)(b * P + p0 + pix)) * COUT + c0] = h;
    }
}

// ---------------------------------------------------------------------------
// Global mean pool, pass 1: partial column sums over pixel chunks (no atomics,
// deterministic).  grid = B*NCH blocks, 256 threads (= C3 channels).
// ---------------------------------------------------------------------------
__global__ __launch_bounds__(256)
void colsum_kernel(const float* __restrict__ h, float* __restrict__ zpart)
{
    int blk = blockIdx.x;
    int b   = blk / NCH, ch = blk % NCH;
    int c   = threadIdx.x;
    const float* __restrict__ base = h + ((size_t)(b * P2 + ch * CHP)) * 256 + c;
    float s = 0.f;
#pragma unroll 4
    for (int p = 0; p < CHP; ++p) s += base[(size_t)p * 256];
    zpart[((size_t)(b * NCH + ch)) * 256 + c] = s;
}

// ---------------------------------------------------------------------------
// Head: z = mean_p(h3); relu(z@mW1+mb1) @ mW2 + mb2.  grid = B, 512 threads.
// ---------------------------------------------------------------------------
__global__ __launch_bounds__(512)
void head_kernel(const float* __restrict__ zpart,
                 const float* __restrict__ mW1, const float* __restrict__ mb1,
                 const float* __restrict__ mW2, const float* __restrict__ mb2,
                 float* __restrict__ out)
{
    __shared__ float zs[256];
    __shared__ float hsh[512];
    int b = blockIdx.x, tid = threadIdx.x;
    if (tid < 256) {
        float s = 0.f;
        for (int ch = 0; ch < NCH; ++ch)
            s += zpart[((size_t)(b * NCH + ch)) * 256 + tid];
        zs[tid] = s * (1.0f / P2);
    }
    __syncthreads();
    {
        float a = mb1[tid];
#pragma unroll 8
        for (int i = 0; i < 256; ++i) a = fmaf(zs[i], mW1[i * 512 + tid], a);
        hsh[tid] = fmaxf(a, 0.f);
    }
    __syncthreads();
    if (tid < 256) {
        float a = mb2[tid];
#pragma unroll 8
        for (int i = 0; i < 512; ++i) a = fmaf(hsh[i], mW2[i * 256 + tid], a);
        out[(size_t)b * 256 + tid] = a;
    }
}

} // anonymous namespace

extern "C" void kernel_launch(void* const* d_in, const int* in_sizes, int n_in,
                              void* d_out, int out_size, void* d_ws, size_t ws_size,
                              hipStream_t stream)
{
    const float* x     = (const float*)d_in[0];
    const int*   cols1 = (const int*)  d_in[1];
    const float* vals1 = (const float*)d_in[2];
    const int*   cols2 = (const int*)  d_in[3];
    const float* vals2 = (const float*)d_in[4];
    const int*   cols3 = (const int*)  d_in[5];
    const float* vals3 = (const float*)d_in[6];
    const float* W1  = (const float*)d_in[7];
    const float* b1  = (const float*)d_in[8];
    const float* g1  = (const float*)d_in[9];
    const float* bt1 = (const float*)d_in[10];
    const float* W2  = (const float*)d_in[11];
    const float* b2  = (const float*)d_in[12];
    const float* g2  = (const float*)d_in[13];
    const float* bt2 = (const float*)d_in[14];
    const float* W3  = (const float*)d_in[15];
    const float* b3  = (const float*)d_in[16];
    const float* g3  = (const float*)d_in[17];
    const float* bt3 = (const float*)d_in[18];
    const float* mW1 = (const float*)d_in[19];
    const float* mb1 = (const float*)d_in[20];
    const float* mW2 = (const float*)d_in[21];
    const float* mb2 = (const float*)d_in[22];
    float* out = (float*)d_out;

    // workspace layout (floats); slot = B*P0*16 = B*P1*64 = 12,582,912 elems
    float* ws = (float*)d_ws;
    const size_t SLOT = (size_t)B * P0 * 16;           // 12,582,912
    float* t_a  = ws;                                  // stage term buffers
    float* t_b  = ws + SLOT;
    float* t_c  = ws + 2 * SLOT;
    float* h1   = ws + 3 * SLOT;                       // (B,P1,64)
    float* h2   = ws + 4 * SLOT;                       // (B,P2,128) = SLOT/2
    float* h3   = ws + 3 * SLOT;                       // reuse h1 slot (dead)
    float* v_a  = ws;                                  // stage-3 terms (smaller)
    float* v_b  = ws + (size_t)B * P2 * 128;
    float* v_c  = ws + 2 * (size_t)B * P2 * 128;
    float* zpart = ws + 4 * SLOT + (size_t)B * P2 * 128;  // 4*NCH*256 floats

    // ---- Stage 1: P0, Cin=16 -> 64, pool 4 ----
    {
        int Cv = 4;  // 16/4
        long tot = (long)B * P0 * Cv;
        int nb = (int)((tot + 255) / 256);
        lmul_kernel<<<nb, 256, 0, stream>>>(x,  nullptr, cols1, vals1, t_a, P0, Cv, 1.f,  0.f);
        lmul_kernel<<<nb, 256, 0, stream>>>(t_a, x,      cols1, vals1, t_b, P0, Cv, 2.f, -1.f);
        lmul_kernel<<<nb, 256, 0, stream>>>(t_b, t_a,    cols1, vals1, t_c, P0, Cv, 2.f, -1.f);
        int grid = B * (P0 / (1024 * 4 / 64));  // PIXB = 64
        cheb_mm_ln_kernel<16, 64, 4, 1024><<<grid, 1024, 0, stream>>>(
            P0, x, t_a, t_b, t_c, W1, b1, g1, bt1, h1);
    }
    // ---- Stage 2: P1, 64 -> 128, pool 4 ----
    {
        int Cv = 16;
        long tot = (long)B * P1 * Cv;
        int nb = (int)((tot + 255) / 256);
        lmul_kernel<<<nb, 256, 0, stream>>>(h1,  nullptr, cols2, vals2, t_a, P1, Cv, 1.f,  0.f);
        lmul_kernel<<<nb, 256, 0, stream>>>(t_a, h1,      cols2, vals2, t_b, P1, Cv, 2.f, -1.f);
        lmul_kernel<<<nb, 256, 0, stream>>>(t_b, t_a,     cols2, vals2, t_c, P1, Cv, 2.f, -1.f);
        int grid = B * (P1 / (1024 * 4 / 128)); // PIXB = 32
        cheb_mm_ln_kernel<64, 128, 4, 1024><<<grid, 1024, 0, stream>>>(
            P1, h1, t_a, t_b, t_c, W2, b2, g2, bt2, h2);
    }
    // ---- Stage 3: P2, 128 -> 256, no pool ----
    {
        int Cv = 32;
        long tot = (long)B * P2 * Cv;
        int nb = (int)((tot + 255) / 256);
        lmul_kernel<<<nb, 256, 0, stream>>>(h2,  nullptr, cols3, vals3, v_a, P2, Cv, 1.f,  0.f);
        lmul_kernel<<<nb, 256, 0, stream>>>(v_a, h2,      cols3, vals3, v_b, P2, Cv, 2.f, -1.f);
        lmul_kernel<<<nb, 256, 0, stream>>>(v_b, v_a,     cols3, vals3, v_c, P2, Cv, 2.f, -1.f);
        int grid = B * (P2 / (1024 * 4 / 256)); // PIXB = 16
        cheb_mm_ln_kernel<128, 256, 1, 1024><<<grid, 1024, 0, stream>>>(
            P2, h2, v_a, v_b, v_c, W3, b3, g3, bt3, h3);
    }
    // ---- Global mean pool + MLP head ----
    colsum_kernel<<<B * NCH, 256, 0, stream>>>(h3, zpart);
    head_kernel<<<B, 512, 0, stream>>>(zpart, mW1, mb1, mW2, mb2, out);

    (void)in_sizes; (void)n_in; (void)out_size; (void)ws_size;
}

// Round 2
// 555.965 us; speedup vs baseline: 4.2719x; 4.2719x over previous
//
#include <hip/hip_runtime.h>
#include <hip/hip_bf16.h>

namespace {

constexpr int B  = 4;
constexpr int P0 = 196608, P1 = 49152, P2 = 12288;
constexpr int DEG = 8;
constexpr float EPS = 1e-5f;
constexpr int NCH = 96;           // colsum chunks per batch
constexpr int CHP = P2 / NCH;     // 128 pixels per chunk

typedef __attribute__((ext_vector_type(4))) float f32x4;
typedef __attribute__((ext_vector_type(8))) short s16x8;

__device__ __forceinline__ float b2f(unsigned short u) {
    union { unsigned int i; float f; } c; c.i = (unsigned int)u << 16; return c.f;
}
__device__ __forceinline__ unsigned short f2b(float f) {
    __hip_bfloat16 h = __float2bfloat16(f);   // RNE
    return *reinterpret_cast<unsigned short*>(&h);
}

// ---------------------------------------------------------------------------
// fp32 -> bf16 convert (vectorized x4)
// ---------------------------------------------------------------------------
__global__ __launch_bounds__(256)
void f2bf_kernel(const float* __restrict__ in, unsigned short* __restrict__ out, long n4)
{
    long i = (long)blockIdx.x * blockDim.x + threadIdx.x;
    if (i >= n4) return;
    float4 v = ((const float4*)in)[i];
    ushort4 o;
    o.x = f2b(v.x); o.y = f2b(v.y); o.z = f2b(v.z); o.w = f2b(v.w);
    ((ushort4*)out)[i] = o;
}

// ---------------------------------------------------------------------------
// W (K,N) fp32 -> Wt (N,K) bf16   (tiny, once per launch)
// ---------------------------------------------------------------------------
__global__ __launch_bounds__(256)
void wt_convert_kernel(const float* __restrict__ W, unsigned short* __restrict__ Wt,
                       int K, int N)
{
    int i = blockIdx.x * blockDim.x + threadIdx.x;
    if (i >= K * N) return;
    int n = i % N, k = i / N;
    Wt[(size_t)n * K + k] = f2b(W[i]);
}

// ---------------------------------------------------------------------------
// Sparse Chebyshev step, bf16 in/out, fp32 accum:
//   out[b,p,:] = alpha * sum_d vals[p,d]*in[b,cols[p,d],:] + beta*prev[b,p,:]
// Channel-vectorized: each thread owns 8 channels (one uint4 = 8 bf16).
// ---------------------------------------------------------------------------
__global__ __launch_bounds__(256)
void lmul_bf16_kernel(const unsigned short* __restrict__ in,
                      const unsigned short* __restrict__ prev,
                      const int* __restrict__ cols, const float* __restrict__ vals,
                      unsigned short* __restrict__ out,
                      int P, int Cv8, float alpha, float beta)
{
    long idx = (long)blockIdx.x * blockDim.x + threadIdx.x;
    long total = (long)B * P * Cv8;
    if (idx >= total) return;
    int v  = (int)(idx % Cv8);
    long r = idx / Cv8;
    int p  = (int)(r % P);
    int b  = (int)(r / P);

    const uint4* in16 = (const uint4*)in;
    const int*   cp = cols + p * DEG;
    const float* vp = vals + p * DEG;

    float acc[8] = {0.f,0.f,0.f,0.f,0.f,0.f,0.f,0.f};
#pragma unroll
    for (int d = 0; d < DEG; ++d) {
        int   col = cp[d];
        float w   = vp[d];
        union { uint4 u; unsigned short s[8]; } x;
        x.u = in16[(size_t)(b * P + col) * Cv8 + v];
#pragma unroll
        for (int j = 0; j < 8; ++j) acc[j] = fmaf(w, b2f(x.s[j]), acc[j]);
    }
    size_t o = (size_t)(b * P + p) * Cv8 + v;
    if (beta != 0.f) {
        union { uint4 u; unsigned short s[8]; } pv;
        pv.u = ((const uint4*)prev)[o];
#pragma unroll
        for (int j = 0; j < 8; ++j)
            acc[j] = fmaf(alpha, acc[j], beta * b2f(pv.s[j]));
    } else if (alpha != 1.f) {
#pragma unroll
        for (int j = 0; j < 8; ++j) acc[j] *= alpha;
    }
    union { uint4 u; unsigned short s[8]; } ou;
#pragma unroll
    for (int j = 0; j < 8; ++j) ou.s[j] = f2b(acc[j]);
    ((uint4*)out)[o] = ou.u;
}

// ---------------------------------------------------------------------------
// Fused MFMA GEMM + bias + LayerNorm + ReLU + optional 4:1 pool.
//   A = concat(t0..t3) (M x KC) bf16, Wt = (COUT x KC) bf16 (pre-transposed).
// Block: 256 threads = 4 waves; wave w owns rows [w*16, w*16+16) of a 64-row
// M-tile, all COUT cols. K processed in 64-wide chunks staged in LDS
// (row stride 72 bf16 = 144B -> ~2-way bank alias, free).
// C/D layout (m89): col=lane&15, row=(lane>>4)*4+reg -> a pool group (4
// consecutive rows) is exactly the 4 accum regs of one lane: pooling is free.
// LN row-sums: shfl_xor masks 1,2,4,8 within 16-lane groups.
// POOL==4: out is bf16 (M/4 x COUT).  POOL==1: out is fp32 (M x COUT).
// ---------------------------------------------------------------------------
template <int CIN, int COUT, int POOL>
__global__ __launch_bounds__(256)
void cheb_mm_mfma_kernel(const unsigned short* __restrict__ t0,
                         const unsigned short* __restrict__ t1,
                         const unsigned short* __restrict__ t2,
                         const unsigned short* __restrict__ t3,
                         const unsigned short* __restrict__ Wt,
                         const float* __restrict__ bias,
                         const float* __restrict__ gam,
                         const float* __restrict__ bet,
                         void* __restrict__ outv)
{
    constexpr int KC   = 4 * CIN;
    constexpr int NF   = COUT / 16;   // N fragments per wave
    constexpr int NKCH = KC / 64;     // K chunks
    constexpr int LDA  = 72;          // padded LDS row stride (bf16)

    __shared__ unsigned short As[64 * LDA];
    __shared__ unsigned short Ws[COUT * LDA];

    const int tid  = threadIdx.x;
    const long m0  = (long)blockIdx.x * 64;
    const int wave = tid >> 6;
    const int lane = tid & 63;
    const int g    = lane >> 4;     // row-group within fragment
    const int c16  = lane & 15;     // col within fragment / A row within tile

    f32x4 acc[NF];
#pragma unroll
    for (int n = 0; n < NF; ++n) {
        float bz = bias[n * 16 + c16];
        acc[n] = (f32x4){bz, bz, bz, bz};
    }

    for (int kc = 0; kc < NKCH; ++kc) {
        if (kc) __syncthreads();
        // ---- stage A chunk: 64 rows x 64 k (8 bf16 per vec unit) ----
#pragma unroll
        for (int i = tid; i < 64 * 8; i += 256) {
            int row = i >> 3, v = i & 7;
            int k = kc * 64 + v * 8;
            int t = k / CIN;                      // CIN is pow2 -> shift
            int c = k & (CIN - 1);
            const unsigned short* src =
                (t == 0) ? t0 : (t == 1) ? t1 : (t == 2) ? t2 : t3;
            *(uint4*)&As[row * LDA + v * 8] =
                *(const uint4*)&src[(size_t)(m0 + row) * CIN + c];
        }
        // ---- stage Wt chunk: COUT rows x 64 k ----
#pragma unroll
        for (int i = tid; i < COUT * 8; i += 256) {
            int co = i >> 3, v = i & 7;
            *(uint4*)&Ws[co * LDA + v * 8] =
                *(const uint4*)&Wt[(size_t)co * KC + kc * 64 + v * 8];
        }
        __syncthreads();
        // ---- MFMA: 2 K-steps x NF ----
#pragma unroll
        for (int ks = 0; ks < 2; ++ks) {
            s16x8 a = *(const s16x8*)&As[(wave * 16 + c16) * LDA + ks * 32 + g * 8];
#pragma unroll
            for (int n = 0; n < NF; ++n) {
                s16x8 bf = *(const s16x8*)&Ws[(n * 16 + c16) * LDA + ks * 32 + g * 8];
                acc[n] = __builtin_amdgcn_mfma_f32_16x16x32_bf16(a, bf, acc[n], 0, 0, 0);
            }
        }
    }

    // ---- LayerNorm statistics (4 rows per lane: row = g*4 + r) ----
    float s[4] = {0,0,0,0}, q[4] = {0,0,0,0};
#pragma unroll
    for (int n = 0; n < NF; ++n)
#pragma unroll
        for (int r = 0; r < 4; ++r) {
            float v = acc[n][r];
            s[r] += v; q[r] += v * v;
        }
#pragma unroll
    for (int msk = 1; msk < 16; msk <<= 1)
#pragma unroll
        for (int r = 0; r < 4; ++r) {
            s[r] += __shfl_xor(s[r], msk, 64);
            q[r] += __shfl_xor(q[r], msk, 64);
        }
    float mu[4], rs[4];
#pragma unroll
    for (int r = 0; r < 4; ++r) {
        mu[r] = s[r] * (1.f / COUT);
        float var = q[r] * (1.f / COUT) - mu[r] * mu[r];
        rs[r] = rsqrtf(var + EPS);
    }

    if constexpr (POOL == 4) {
        unsigned short* out = (unsigned short*)outv;
#pragma unroll
        for (int n = 0; n < NF; ++n) {
            float gv = gam[n * 16 + c16], bv = bet[n * 16 + c16];
            float pv = 0.f;
#pragma unroll
            for (int r = 0; r < 4; ++r) {
                float h = fmaf(gv * rs[r], acc[n][r] - mu[r], bv);
                pv += fmaxf(h, 0.f);
            }
            out[(size_t)(m0 / 4 + wave * 4 + g) * COUT + n * 16 + c16] = f2b(pv * 0.25f);
        }
    } else {
        float* out = (float*)outv;
#pragma unroll
        for (int n = 0; n < NF; ++n) {
            float gv = gam[n * 16 + c16], bv = bet[n * 16 + c16];
#pragma unroll
            for (int r = 0; r < 4; ++r) {
                float h = fmaf(gv * rs[r], acc[n][r] - mu[r], bv);
                out[(size_t)(m0 + wave * 16 + g * 4 + r) * COUT + n * 16 + c16] =
                    fmaxf(h, 0.f);
            }
        }
    }
}

// ---------------------------------------------------------------------------
// Global mean pool pass 1: deterministic partial column sums.
// ---------------------------------------------------------------------------
__global__ __launch_bounds__(256)
void colsum_kernel(const float* __restrict__ h, float* __restrict__ zpart)
{
    int blk = blockIdx.x;
    int b   = blk / NCH, ch = blk % NCH;
    int c   = threadIdx.x;
    const float* __restrict__ base = h + ((size_t)(b * P2 + ch * CHP)) * 256 + c;
    float s = 0.f;
#pragma unroll 4
    for (int p = 0; p < CHP; ++p) s += base[(size_t)p * 256];
    zpart[((size_t)(b * NCH + ch)) * 256 + c] = s;
}

// ---------------------------------------------------------------------------
// Head: z = mean_p(h3); relu(z@mW1+mb1) @ mW2 + mb2.
// ---------------------------------------------------------------------------
__global__ __launch_bounds__(512)
void head_kernel(const float* __restrict__ zpart,
                 const float* __restrict__ mW1, const float* __restrict__ mb1,
                 const float* __restrict__ mW2, const float* __restrict__ mb2,
                 float* __restrict__ out)
{
    __shared__ float zs[256];
    __shared__ float hsh[512];
    int b = blockIdx.x, tid = threadIdx.x;
    if (tid < 256) {
        float s = 0.f;
        for (int ch = 0; ch < NCH; ++ch)
            s += zpart[((size_t)(b * NCH + ch)) * 256 + tid];
        zs[tid] = s * (1.0f / P2);
    }
    __syncthreads();
    {
        float a = mb1[tid];
#pragma unroll 8
        for (int i = 0; i < 256; ++i) a = fmaf(zs[i], mW1[i * 512 + tid], a);
        hsh[tid] = fmaxf(a, 0.f);
    }
    __syncthreads();
    if (tid < 256) {
        float a = mb2[tid];
#pragma unroll 8
        for (int i = 0; i < 512; ++i) a = fmaf(hsh[i], mW2[i * 256 + tid], a);
        out[(size_t)b * 256 + tid] = a;
    }
}

} // anonymous namespace

extern "C" void kernel_launch(void* const* d_in, const int* in_sizes, int n_in,
                              void* d_out, int out_size, void* d_ws, size_t ws_size,
                              hipStream_t stream)
{
    const float* x     = (const float*)d_in[0];
    const int*   cols1 = (const int*)  d_in[1];
    const float* vals1 = (const float*)d_in[2];
    const int*   cols2 = (const int*)  d_in[3];
    const float* vals2 = (const float*)d_in[4];
    const int*   cols3 = (const int*)  d_in[5];
    const float* vals3 = (const float*)d_in[6];
    const float* W1  = (const float*)d_in[7];
    const float* b1  = (const float*)d_in[8];
    const float* g1  = (const float*)d_in[9];
    const float* bt1 = (const float*)d_in[10];
    const float* W2  = (const float*)d_in[11];
    const float* b2  = (const float*)d_in[12];
    const float* g2  = (const float*)d_in[13];
    const float* bt2 = (const float*)d_in[14];
    const float* W3  = (const float*)d_in[15];
    const float* b3  = (const float*)d_in[16];
    const float* g3  = (const float*)d_in[17];
    const float* bt3 = (const float*)d_in[18];
    const float* mW1 = (const float*)d_in[19];
    const float* mb1 = (const float*)d_in[20];
    const float* mW2 = (const float*)d_in[21];
    const float* mb2 = (const float*)d_in[22];
    float* out = (float*)d_out;

    // ---- workspace layout (256B-aligned slots) ----
    char* w = (char*)d_ws;
    size_t off = 0;
    auto alloc = [&](size_t bytes) -> void* {
        void* p = w + off;
        off += (bytes + 255) & ~(size_t)255;
        return p;
    };
    const size_t E1 = (size_t)B * P0 * 16;   // 12,582,912 elems
    unsigned short* xb  = (unsigned short*)alloc(E1 * 2);
    unsigned short* t_a = (unsigned short*)alloc(E1 * 2);
    unsigned short* t_b = (unsigned short*)alloc(E1 * 2);
    unsigned short* t_c = (unsigned short*)alloc(E1 * 2);
    unsigned short* h1  = (unsigned short*)alloc((size_t)B * P1 * 64 * 2);
    unsigned short* h2  = (unsigned short*)alloc((size_t)B * P2 * 128 * 2);
    float*          h3  = (float*)alloc((size_t)B * P2 * 256 * 4);
    unsigned short* Wt1 = (unsigned short*)alloc(64 * 64 * 2);
    unsigned short* Wt2 = (unsigned short*)alloc(256 * 128 * 2);
    unsigned short* Wt3 = (unsigned short*)alloc(512 * 256 * 2);
    float*        zpart = (float*)alloc((size_t)B * NCH * 256 * 4);

    // ---- precompute bf16 copies ----
    f2bf_kernel<<<(int)((E1 / 4 + 255) / 256), 256, 0, stream>>>(x, xb, (long)(E1 / 4));
    wt_convert_kernel<<<(64 * 64 + 255) / 256, 256, 0, stream>>>(W1, Wt1, 64, 64);
    wt_convert_kernel<<<(256 * 128 + 255) / 256, 256, 0, stream>>>(W2, Wt2, 256, 128);
    wt_convert_kernel<<<(512 * 256 + 255) / 256, 256, 0, stream>>>(W3, Wt3, 512, 256);

    // ---- Stage 1: P0, 16 -> 64, pool 4 ----
    {
        int Cv8 = 2;
        long tot = (long)B * P0 * Cv8;
        int nb = (int)((tot + 255) / 256);
        lmul_bf16_kernel<<<nb, 256, 0, stream>>>(xb,  nullptr, cols1, vals1, t_a, P0, Cv8, 1.f,  0.f);
        lmul_bf16_kernel<<<nb, 256, 0, stream>>>(t_a, xb,      cols1, vals1, t_b, P0, Cv8, 2.f, -1.f);
        lmul_bf16_kernel<<<nb, 256, 0, stream>>>(t_b, t_a,     cols1, vals1, t_c, P0, Cv8, 2.f, -1.f);
        cheb_mm_mfma_kernel<16, 64, 4><<<(B * P0) / 64, 256, 0, stream>>>(
            xb, t_a, t_b, t_c, Wt1, b1, g1, bt1, h1);
    }
    // ---- Stage 2: P1, 64 -> 128, pool 4 ----
    {
        int Cv8 = 8;
        long tot = (long)B * P1 * Cv8;
        int nb = (int)((tot + 255) / 256);
        lmul_bf16_kernel<<<nb, 256, 0, stream>>>(h1,  nullptr, cols2, vals2, t_a, P1, Cv8, 1.f,  0.f);
        lmul_bf16_kernel<<<nb, 256, 0, stream>>>(t_a, h1,      cols2, vals2, t_b, P1, Cv8, 2.f, -1.f);
        lmul_bf16_kernel<<<nb, 256, 0, stream>>>(t_b, t_a,     cols2, vals2, t_c, P1, Cv8, 2.f, -1.f);
        cheb_mm_mfma_kernel<64, 128, 4><<<(B * P1) / 64, 256, 0, stream>>>(
            h1, t_a, t_b, t_c, Wt2, b2, g2, bt2, h2);
    }
    // ---- Stage 3: P2, 128 -> 256, no pool ----
    {
        int Cv8 = 16;
        long tot = (long)B * P2 * Cv8;
        int nb = (int)((tot + 255) / 256);
        lmul_bf16_kernel<<<nb, 256, 0, stream>>>(h2,  nullptr, cols3, vals3, t_a, P2, Cv8, 1.f,  0.f);
        lmul_bf16_kernel<<<nb, 256, 0, stream>>>(t_a, h2,      cols3, vals3, t_b, P2, Cv8, 2.f, -1.f);
        lmul_bf16_kernel<<<nb, 256, 0, stream>>>(t_b, t_a,     cols3, vals3, t_c, P2, Cv8, 2.f, -1.f);
        cheb_mm_mfma_kernel<128, 256, 1><<<(B * P2) / 64, 256, 0, stream>>>(
            h2, t_a, t_b, t_c, Wt3, b3, g3, bt3, h3);
    }
    // ---- Global mean pool + MLP head ----
    colsum_kernel<<<B * NCH, 256, 0, stream>>>(h3, zpart);
    head_kernel<<<B, 512, 0, stream>>>(zpart, mW1, mb1, mW2, mb2, out);

    (void)in_sizes; (void)n_in; (void)out_size; (void)ws_size;
}

// Round 3
// 464.552 us; speedup vs baseline: 5.1125x; 1.1968x over previous
//
#include <hip/hip_runtime.h>
#include <hip/hip_bf16.h>

namespace {

constexpr int B  = 4;
constexpr int P0 = 196608, P1 = 49152, P2 = 12288;
constexpr int DEG = 8;
constexpr float EPS = 1e-5f;
constexpr int NCH = 96;           // colsum chunks per batch
constexpr int CHP = P2 / NCH;     // 128 pixels per chunk

typedef __attribute__((ext_vector_type(4))) float f32x4;
typedef __attribute__((ext_vector_type(8))) short s16x8;

__device__ __forceinline__ float b2f(unsigned short u) {
    union { unsigned int i; float f; } c; c.i = (unsigned int)u << 16; return c.f;
}
__device__ __forceinline__ unsigned short f2b(float f) {
    __hip_bfloat16 h = __float2bfloat16(f);   // RNE
    return *reinterpret_cast<unsigned short*>(&h);
}

// ---------------------------------------------------------------------------
// x: (B,P0,16) fp32  ->  xb: (P0,B,16) bf16   (batch-interleaved layout)
// thread = (p, b, half): writes one uint4 (8 bf16), fully coalesced writes.
// ---------------------------------------------------------------------------
__global__ __launch_bounds__(256)
void x2p_kernel(const float* __restrict__ in, unsigned short* __restrict__ out)
{
    long idx = (long)blockIdx.x * blockDim.x + threadIdx.x;   // P0*B*2 total
    if (idx >= (long)P0 * B * 2) return;
    int  h = (int)(idx & 1);
    int  b = (int)((idx >> 1) & 3);
    long p = idx >> 3;
    const float* src = in + ((size_t)b * P0 + p) * 16 + h * 8;
    float4 v0 = *(const float4*)src;
    float4 v1 = *(const float4*)(src + 4);
    union { uint4 u; unsigned short s[8]; } o;
    o.s[0] = f2b(v0.x); o.s[1] = f2b(v0.y); o.s[2] = f2b(v0.z); o.s[3] = f2b(v0.w);
    o.s[4] = f2b(v1.x); o.s[5] = f2b(v1.y); o.s[6] = f2b(v1.z); o.s[7] = f2b(v1.w);
    *(uint4*)&out[((size_t)p * B + b) * 16 + h * 8] = o.u;
}

// ---------------------------------------------------------------------------
// W (K,N) fp32 -> Wt (N,K) bf16   (tiny, once per launch)
// ---------------------------------------------------------------------------
__global__ __launch_bounds__(256)
void wt_convert_kernel(const float* __restrict__ W, unsigned short* __restrict__ Wt,
                       int K, int N)
{
    int i = blockIdx.x * blockDim.x + threadIdx.x;
    if (i >= K * N) return;
    int n = i % N, k = i / N;
    Wt[(size_t)n * K + k] = f2b(W[i]);
}

// ---------------------------------------------------------------------------
// Sparse Chebyshev step on (P, B*C) bf16 rows, fp32 accum:
//   out[p,:] = alpha * sum_d vals[p,d] * in[cols[p,d],:] + beta * prev[p,:]
// Row = B*C contiguous bf16 -> every tap reads a fully-used contiguous block
// (128B at C=16). Cv8 = B*C/8 uint4-units per row; thread owns one unit.
// ---------------------------------------------------------------------------
__global__ __launch_bounds__(256)
void lmul_bf16_kernel(const unsigned short* __restrict__ in,
                      const unsigned short* __restrict__ prev,
                      const int* __restrict__ cols, const float* __restrict__ vals,
                      unsigned short* __restrict__ out,
                      int P, int Cv8, float alpha, float beta)
{
    long idx = (long)blockIdx.x * blockDim.x + threadIdx.x;
    long total = (long)P * Cv8;
    if (idx >= total) return;
    int v = (int)(idx % Cv8);
    int p = (int)(idx / Cv8);

    const uint4* in16 = (const uint4*)in;
    const int*   cp = cols + p * DEG;
    const float* vp = vals + p * DEG;

    float acc[8] = {0.f,0.f,0.f,0.f,0.f,0.f,0.f,0.f};
#pragma unroll
    for (int d = 0; d < DEG; ++d) {
        int   col = cp[d];
        float w   = vp[d];
        union { uint4 u; unsigned short s[8]; } x;
        x.u = in16[(size_t)col * Cv8 + v];
#pragma unroll
        for (int j = 0; j < 8; ++j) acc[j] = fmaf(w, b2f(x.s[j]), acc[j]);
    }
    size_t o = (size_t)p * Cv8 + v;
    if (beta != 0.f) {
        union { uint4 u; unsigned short s[8]; } pv;
        pv.u = ((const uint4*)prev)[o];
#pragma unroll
        for (int j = 0; j < 8; ++j)
            acc[j] = fmaf(alpha, acc[j], beta * b2f(pv.s[j]));
    } else if (alpha != 1.f) {
#pragma unroll
        for (int j = 0; j < 8; ++j) acc[j] *= alpha;
    }
    union { uint4 u; unsigned short s[8]; } ou;
#pragma unroll
    for (int j = 0; j < 8; ++j) ou.s[j] = f2b(acc[j]);
    ((uint4*)out)[o] = ou.u;
}

// ---------------------------------------------------------------------------
// Fused MFMA GEMM + bias + LayerNorm + ReLU + optional 4:1 pool, on (P,B,C).
// Block = 256 thr = 4 waves, owns 16 pixels x 4 batches = 64 A-rows.
// LDS row r <-> (pixel = pblk + (r>>4)*4 + (r&3), batch = (r>>2)&3), so
// MFMA output row r = w*16 + g*4 + i gives: lane (w,g) holds 4 regs =
// 4 consecutive pixels (a pool group) of batch g -> in-register pooling.
// LN row-stats: shfl_xor masks 1,2,4,8 within 16-lane groups (per reg).
// POOL==4: bf16 out (P/4, B, COUT).  POOL==1: fp32 out (P, B, COUT).
// ---------------------------------------------------------------------------
template <int CIN, int COUT, int POOL, int LOG2CIN>
__global__ __launch_bounds__(256)
void cheb_mm_mfma_kernel(const unsigned short* __restrict__ t0,
                         const unsigned short* __restrict__ t1,
                         const unsigned short* __restrict__ t2,
                         const unsigned short* __restrict__ t3,
                         const unsigned short* __restrict__ Wt,
                         const float* __restrict__ bias,
                         const float* __restrict__ gam,
                         const float* __restrict__ bet,
                         void* __restrict__ outv)
{
    constexpr int KC   = 4 * CIN;
    constexpr int NF   = COUT / 16;   // N fragments per wave
    constexpr int NKCH = KC / 64;     // K chunks
    constexpr int LDA  = 72;          // padded LDS row stride (bf16); 144B = 9x16B

    __shared__ unsigned short As[64 * LDA];
    __shared__ unsigned short Ws[COUT * LDA];

    const int tid  = threadIdx.x;
    const int pblk = blockIdx.x * 16;
    const int wave = tid >> 6;
    const int lane = tid & 63;
    const int g    = lane >> 4;     // row-group (= batch of this lane's rows)
    const int c16  = lane & 15;

    f32x4 acc[NF];
#pragma unroll
    for (int n = 0; n < NF; ++n) {
        float bz = bias[n * 16 + c16];
        acc[n] = (f32x4){bz, bz, bz, bz};
    }

    for (int kc = 0; kc < NKCH; ++kc) {
        if (kc) __syncthreads();
        // ---- stage A chunk: 64 rows x 64 k ----
#pragma unroll
        for (int i = tid; i < 64 * 8; i += 256) {
            int row = i >> 3, v = i & 7;
            int k = kc * 64 + v * 8;
            int t = k >> LOG2CIN;
            int c = k & (CIN - 1);
            int pix = pblk + ((row >> 4) << 2) + (row & 3);
            int bb  = (row >> 2) & 3;
            const unsigned short* src =
                (t == 0) ? t0 : (t == 1) ? t1 : (t == 2) ? t2 : t3;
            *(uint4*)&As[row * LDA + v * 8] =
                *(const uint4*)&src[((size_t)pix * B + bb) * CIN + c];
        }
        // ---- stage Wt chunk: COUT rows x 64 k ----
#pragma unroll
        for (int i = tid; i < COUT * 8; i += 256) {
            int co = i >> 3, v = i & 7;
            *(uint4*)&Ws[co * LDA + v * 8] =
                *(const uint4*)&Wt[(size_t)co * KC + kc * 64 + v * 8];
        }
        __syncthreads();
        // ---- MFMA: 2 K-steps x NF ----
#pragma unroll
        for (int ks = 0; ks < 2; ++ks) {
            s16x8 a = *(const s16x8*)&As[(wave * 16 + c16) * LDA + ks * 32 + g * 8];
#pragma unroll
            for (int n = 0; n < NF; ++n) {
                s16x8 bf = *(const s16x8*)&Ws[(n * 16 + c16) * LDA + ks * 32 + g * 8];
                acc[n] = __builtin_amdgcn_mfma_f32_16x16x32_bf16(a, bf, acc[n], 0, 0, 0);
            }
        }
    }

    // ---- LayerNorm statistics (reg r = pixel pblk + wave*4 + r, batch g) ----
    float s[4] = {0,0,0,0}, q[4] = {0,0,0,0};
#pragma unroll
    for (int n = 0; n < NF; ++n)
#pragma unroll
        for (int r = 0; r < 4; ++r) {
            float v = acc[n][r];
            s[r] += v; q[r] += v * v;
        }
#pragma unroll
    for (int msk = 1; msk < 16; msk <<= 1)
#pragma unroll
        for (int r = 0; r < 4; ++r) {
            s[r] += __shfl_xor(s[r], msk, 64);
            q[r] += __shfl_xor(q[r], msk, 64);
        }
    float mu[4], rs[4];
#pragma unroll
    for (int r = 0; r < 4; ++r) {
        mu[r] = s[r] * (1.f / COUT);
        float var = q[r] * (1.f / COUT) - mu[r] * mu[r];
        rs[r] = rsqrtf(var + EPS);
    }

    if constexpr (POOL == 4) {
        // pooled pixel = blockIdx.x*4 + wave, batch = g
        unsigned short* out = (unsigned short*)outv;
        size_t rowo = ((size_t)(blockIdx.x * 4 + wave) * B + g) * COUT;
#pragma unroll
        for (int n = 0; n < NF; ++n) {
            float gv = gam[n * 16 + c16], bv = bet[n * 16 + c16];
            float pv = 0.f;
#pragma unroll
            for (int r = 0; r < 4; ++r) {
                float h = fmaf(gv * rs[r], acc[n][r] - mu[r], bv);
                pv += fmaxf(h, 0.f);
            }
            out[rowo + n * 16 + c16] = f2b(pv * 0.25f);
        }
    } else {
        float* out = (float*)outv;
#pragma unroll
        for (int n = 0; n < NF; ++n) {
            float gv = gam[n * 16 + c16], bv = bet[n * 16 + c16];
#pragma unroll
            for (int r = 0; r < 4; ++r) {
                float h = fmaf(gv * rs[r], acc[n][r] - mu[r], bv);
                out[((size_t)(pblk + wave * 4 + r) * B + g) * COUT + n * 16 + c16] =
                    fmaxf(h, 0.f);
            }
        }
    }
}

// ---------------------------------------------------------------------------
// Global mean pool pass 1 on (P2,B,256) fp32: deterministic partial col sums.
// ---------------------------------------------------------------------------
__global__ __launch_bounds__(256)
void colsum_kernel(const float* __restrict__ h, float* __restrict__ zpart)
{
    int blk = blockIdx.x;
    int b   = blk / NCH, ch = blk % NCH;
    int c   = threadIdx.x;
    const float* __restrict__ base =
        h + ((size_t)(ch * CHP) * B + b) * 256 + c;
    float s = 0.f;
#pragma unroll 4
    for (int p = 0; p < CHP; ++p) s += base[(size_t)p * B * 256];
    zpart[((size_t)(b * NCH + ch)) * 256 + c] = s;
}

// ---------------------------------------------------------------------------
// Head: z = mean_p(h3); relu(z@mW1+mb1) @ mW2 + mb2.
// ---------------------------------------------------------------------------
__global__ __launch_bounds__(512)
void head_kernel(const float* __restrict__ zpart,
                 const float* __restrict__ mW1, const float* __restrict__ mb1,
                 const float* __restrict__ mW2, const float* __restrict__ mb2,
                 float* __restrict__ out)
{
    __shared__ float zs[256];
    __shared__ float hsh[512];
    int b = blockIdx.x, tid = threadIdx.x;
    if (tid < 256) {
        float s = 0.f;
        for (int ch = 0; ch < NCH; ++ch)
            s += zpart[((size_t)(b * NCH + ch)) * 256 + tid];
        zs[tid] = s * (1.0f / P2);
    }
    __syncthreads();
    {
        float a = mb1[tid];
#pragma unroll 8
        for (int i = 0; i < 256; ++i) a = fmaf(zs[i], mW1[i * 512 + tid], a);
        hsh[tid] = fmaxf(a, 0.f);
    }
    __syncthreads();
    if (tid < 256) {
        float a = mb2[tid];
#pragma unroll 8
        for (int i = 0; i < 512; ++i) a = fmaf(hsh[i], mW2[i * 256 + tid], a);
        out[(size_t)b * 256 + tid] = a;
    }
}

} // anonymous namespace

extern "C" void kernel_launch(void* const* d_in, const int* in_sizes, int n_in,
                              void* d_out, int out_size, void* d_ws, size_t ws_size,
                              hipStream_t stream)
{
    const float* x     = (const float*)d_in[0];
    const int*   cols1 = (const int*)  d_in[1];
    const float* vals1 = (const float*)d_in[2];
    const int*   cols2 = (const int*)  d_in[3];
    const float* vals2 = (const float*)d_in[4];
    const int*   cols3 = (const int*)  d_in[5];
    const float* vals3 = (const float*)d_in[6];
    const float* W1  = (const float*)d_in[7];
    const float* b1  = (const float*)d_in[8];
    const float* g1  = (const float*)d_in[9];
    const float* bt1 = (const float*)d_in[10];
    const float* W2  = (const float*)d_in[11];
    const float* b2  = (const float*)d_in[12];
    const float* g2  = (const float*)d_in[13];
    const float* bt2 = (const float*)d_in[14];
    const float* W3  = (const float*)d_in[15];
    const float* b3  = (const float*)d_in[16];
    const float* g3  = (const float*)d_in[17];
    const float* bt3 = (const float*)d_in[18];
    const float* mW1 = (const float*)d_in[19];
    const float* mb1 = (const float*)d_in[20];
    const float* mW2 = (const float*)d_in[21];
    const float* mb2 = (const float*)d_in[22];
    float* out = (float*)d_out;

    // ---- workspace layout (256B-aligned slots) ----
    char* w = (char*)d_ws;
    size_t off = 0;
    auto alloc = [&](size_t bytes) -> void* {
        void* p = w + off;
        off += (bytes + 255) & ~(size_t)255;
        return p;
    };
    const size_t E1 = (size_t)B * P0 * 16;   // 12,582,912 elems
    unsigned short* xb  = (unsigned short*)alloc(E1 * 2);        // (P0,B,16)
    unsigned short* t_a = (unsigned short*)alloc(E1 * 2);
    unsigned short* t_b = (unsigned short*)alloc(E1 * 2);
    unsigned short* t_c = (unsigned short*)alloc(E1 * 2);
    unsigned short* h1  = (unsigned short*)alloc((size_t)P1 * B * 64 * 2);   // (P1,B,64)
    unsigned short* h2  = (unsigned short*)alloc((size_t)P2 * B * 128 * 2);  // (P2,B,128)
    float*          h3  = (float*)alloc((size_t)P2 * B * 256 * 4);           // (P2,B,256)
    unsigned short* Wt1 = (unsigned short*)alloc(64 * 64 * 2);
    unsigned short* Wt2 = (unsigned short*)alloc(256 * 128 * 2);
    unsigned short* Wt3 = (unsigned short*)alloc(512 * 256 * 2);
    float*        zpart = (float*)alloc((size_t)B * NCH * 256 * 4);

    // ---- precompute: layout transpose + bf16 weights ----
    x2p_kernel<<<(int)(((long)P0 * B * 2 + 255) / 256), 256, 0, stream>>>(x, xb);
    wt_convert_kernel<<<(64 * 64 + 255) / 256, 256, 0, stream>>>(W1, Wt1, 64, 64);
    wt_convert_kernel<<<(256 * 128 + 255) / 256, 256, 0, stream>>>(W2, Wt2, 256, 128);
    wt_convert_kernel<<<(512 * 256 + 255) / 256, 256, 0, stream>>>(W3, Wt3, 512, 256);

    // ---- Stage 1: P0, 16 -> 64, pool 4 ----
    {
        int Cv8 = B * 16 / 8;   // 8
        long tot = (long)P0 * Cv8;
        int nb = (int)((tot + 255) / 256);
        lmul_bf16_kernel<<<nb, 256, 0, stream>>>(xb,  nullptr, cols1, vals1, t_a, P0, Cv8, 1.f,  0.f);
        lmul_bf16_kernel<<<nb, 256, 0, stream>>>(t_a, xb,      cols1, vals1, t_b, P0, Cv8, 2.f, -1.f);
        lmul_bf16_kernel<<<nb, 256, 0, stream>>>(t_b, t_a,     cols1, vals1, t_c, P0, Cv8, 2.f, -1.f);
        cheb_mm_mfma_kernel<16, 64, 4, 4><<<P0 / 16, 256, 0, stream>>>(
            xb, t_a, t_b, t_c, Wt1, b1, g1, bt1, h1);
    }
    // ---- Stage 2: P1, 64 -> 128, pool 4 ----
    {
        int Cv8 = B * 64 / 8;   // 32
        long tot = (long)P1 * Cv8;
        int nb = (int)((tot + 255) / 256);
        lmul_bf16_kernel<<<nb, 256, 0, stream>>>(h1,  nullptr, cols2, vals2, t_a, P1, Cv8, 1.f,  0.f);
        lmul_bf16_kernel<<<nb, 256, 0, stream>>>(t_a, h1,      cols2, vals2, t_b, P1, Cv8, 2.f, -1.f);
        lmul_bf16_kernel<<<nb, 256, 0, stream>>>(t_b, t_a,     cols2, vals2, t_c, P1, Cv8, 2.f, -1.f);
        cheb_mm_mfma_kernel<64, 128, 4, 6><<<P1 / 16, 256, 0, stream>>>(
            h1, t_a, t_b, t_c, Wt2, b2, g2, bt2, h2);
    }
    // ---- Stage 3: P2, 128 -> 256, no pool ----
    {
        int Cv8 = B * 128 / 8;  // 64
        long tot = (long)P2 * Cv8;
        int nb = (int)((tot + 255) / 256);
        lmul_bf16_kernel<<<nb, 256, 0, stream>>>(h2,  nullptr, cols3, vals3, t_a, P2, Cv8, 1.f,  0.f);
        lmul_bf16_kernel<<<nb, 256, 0, stream>>>(t_a, h2,      cols3, vals3, t_b, P2, Cv8, 2.f, -1.f);
        lmul_bf16_kernel<<<nb, 256, 0, stream>>>(t_b, t_a,     cols3, vals3, t_c, P2, Cv8, 2.f, -1.f);
        cheb_mm_mfma_kernel<128, 256, 1, 7><<<P2 / 16, 256, 0, stream>>>(
            h2, t_a, t_b, t_c, Wt3, b3, g3, bt3, h3);
    }
    // ---- Global mean pool + MLP head ----
    colsum_kernel<<<B * NCH, 256, 0, stream>>>(h3, zpart);
    head_kernel<<<B, 512, 0, stream>>>(zpart, mW1, mb1, mW2, mb2, out);

    (void)in_sizes; (void)n_in; (void)out_size; (void)ws_size;
}

// Round 4
// 459.806 us; speedup vs baseline: 5.1652x; 1.0103x over previous
//
#include <hip/hip_runtime.h>
#include <hip/hip_bf16.h>

namespace {

constexpr int B  = 4;
constexpr int P0 = 196608, P1 = 49152, P2 = 12288;
constexpr int DEG = 8;
constexpr float EPS = 1e-5f;
constexpr int NBLK3 = (P2 * B) / 64;   // 768 stage-3 blocks -> zblk partials

typedef __attribute__((ext_vector_type(4))) float f32x4;
typedef __attribute__((ext_vector_type(8))) short s16x8;

__device__ __forceinline__ float b2f(unsigned short u) {
    union { unsigned int i; float f; } c; c.i = (unsigned int)u << 16; return c.f;
}
__device__ __forceinline__ unsigned short f2b(float f) {
    __hip_bfloat16 h = __float2bfloat16(f);   // RNE
    return *reinterpret_cast<unsigned short*>(&h);
}

// ---------------------------------------------------------------------------
// x: (B,P0,16) fp32  ->  xb: (P0,B,16) bf16
// ---------------------------------------------------------------------------
__global__ __launch_bounds__(256)
void x2p_kernel(const float* __restrict__ in, unsigned short* __restrict__ out)
{
    long idx = (long)blockIdx.x * blockDim.x + threadIdx.x;   // P0*B*2 total
    if (idx >= (long)P0 * B * 2) return;
    int  h = (int)(idx & 1);
    int  b = (int)((idx >> 1) & 3);
    long p = idx >> 3;
    const float* src = in + ((size_t)b * P0 + p) * 16 + h * 8;
    float4 v0 = *(const float4*)src;
    float4 v1 = *(const float4*)(src + 4);
    union { uint4 u; unsigned short s[8]; } o;
    o.s[0] = f2b(v0.x); o.s[1] = f2b(v0.y); o.s[2] = f2b(v0.z); o.s[3] = f2b(v0.w);
    o.s[4] = f2b(v1.x); o.s[5] = f2b(v1.y); o.s[6] = f2b(v1.z); o.s[7] = f2b(v1.w);
    *(uint4*)&out[((size_t)p * B + b) * 16 + h * 8] = o.u;
}

// ---------------------------------------------------------------------------
// All three W (K,N) fp32 -> Wt (N,K) bf16 in one launch.
// ---------------------------------------------------------------------------
__global__ __launch_bounds__(256)
void wt_all_kernel(const float* __restrict__ W1, const float* __restrict__ W2,
                   const float* __restrict__ W3,
                   unsigned short* __restrict__ Wt1, unsigned short* __restrict__ Wt2,
                   unsigned short* __restrict__ Wt3)
{
    int i = blockIdx.x * 256 + threadIdx.x;
    if (i < 4096) {                       // W1: 64x64
        int n = i % 64, k = i / 64;
        Wt1[n * 64 + k] = f2b(W1[i]);
    } else if (i < 4096 + 32768) {        // W2: 256x128
        int j = i - 4096;
        int n = j % 128, k = j / 128;
        Wt2[n * 256 + k] = f2b(W2[j]);
    } else if (i < 4096 + 32768 + 131072) {  // W3: 512x256
        int j = i - 36864;
        int n = j % 256, k = j / 256;
        Wt3[n * 512 + k] = f2b(W3[j]);
    }
}

// ---------------------------------------------------------------------------
// Sparse Chebyshev step on (P, B*C) bf16 rows, fp32 accum.
// ---------------------------------------------------------------------------
__global__ __launch_bounds__(256)
void lmul_bf16_kernel(const unsigned short* __restrict__ in,
                      const unsigned short* __restrict__ prev,
                      const int* __restrict__ cols, const float* __restrict__ vals,
                      unsigned short* __restrict__ out,
                      int P, int Cv8, float alpha, float beta)
{
    long idx = (long)blockIdx.x * blockDim.x + threadIdx.x;
    long total = (long)P * Cv8;
    if (idx >= total) return;
    int v = (int)(idx % Cv8);
    int p = (int)(idx / Cv8);

    const uint4* in16 = (const uint4*)in;
    const int*   cp = cols + p * DEG;
    const float* vp = vals + p * DEG;

    float acc[8] = {0.f,0.f,0.f,0.f,0.f,0.f,0.f,0.f};
#pragma unroll
    for (int d = 0; d < DEG; ++d) {
        int   col = cp[d];
        float w   = vp[d];
        union { uint4 u; unsigned short s[8]; } x;
        x.u = in16[(size_t)col * Cv8 + v];
#pragma unroll
        for (int j = 0; j < 8; ++j) acc[j] = fmaf(w, b2f(x.s[j]), acc[j]);
    }
    size_t o = (size_t)p * Cv8 + v;
    if (beta != 0.f) {
        union { uint4 u; unsigned short s[8]; } pv;
        pv.u = ((const uint4*)prev)[o];
#pragma unroll
        for (int j = 0; j < 8; ++j)
            acc[j] = fmaf(alpha, acc[j], beta * b2f(pv.s[j]));
    } else if (alpha != 1.f) {
#pragma unroll
        for (int j = 0; j < 8; ++j) acc[j] *= alpha;
    }
    union { uint4 u; unsigned short s[8]; } ou;
#pragma unroll
    for (int j = 0; j < 8; ++j) ou.s[j] = f2b(acc[j]);
    ((uint4*)out)[o] = ou.u;
}

// ---------------------------------------------------------------------------
// Stage-1 fused MM: KC=64, COUT=64, pool 4. W resident in 32 VGPR/lane,
// A-fragments read DIRECTLY from global (no LDS, no barriers). Each wave
// independently processes tiles of 16 rows = 4 pixels x 4 batches,
// grid-stride. Pool over acc regs (4 consecutive pixels), batch = lane>>4.
// out: (P0/4, B, 64) bf16.
// ---------------------------------------------------------------------------
__global__ __launch_bounds__(256)
void s1_mm_kernel(const unsigned short* __restrict__ t0,
                  const unsigned short* __restrict__ t1,
                  const unsigned short* __restrict__ t2,
                  const unsigned short* __restrict__ t3,
                  const unsigned short* __restrict__ Wt,
                  const float* __restrict__ bias,
                  const float* __restrict__ gam,
                  const float* __restrict__ bet,
                  unsigned short* __restrict__ out)
{
    const int wave = threadIdx.x >> 6;
    const int lane = threadIdx.x & 63;
    const int g    = lane >> 4;
    const int c16  = lane & 15;

    // W fragments: wf[ks][n] = Wt[(n*16+c16), ks*32+g*8 .. +8]
    s16x8 wf[2][4];
#pragma unroll
    for (int ks = 0; ks < 2; ++ks)
#pragma unroll
        for (int n = 0; n < 4; ++n)
            wf[ks][n] = *(const s16x8*)&Wt[(size_t)(n * 16 + c16) * 64 + ks * 32 + g * 8];

    float bz[4], gz[4], tz[4];
#pragma unroll
    for (int n = 0; n < 4; ++n) {
        bz[n] = bias[n * 16 + c16];
        gz[n] = gam [n * 16 + c16];
        tz[n] = bet [n * 16 + c16];
    }

    const unsigned short* tb[4] = { t0, t1, t2, t3 };
    const int term0  = g >> 1;          // ks=0 term index
    const int coloff = (g & 1) * 8;
    const int bb     = c16 >> 2;        // A-row batch
    const int px     = c16 & 3;         // A-row pixel within tile

    constexpr int NT = P0 / 4;          // 49152 wave-tiles
    const int wg     = blockIdx.x * 4 + wave;
    const int wstep  = gridDim.x * 4;

    for (int t = wg; t < NT; t += wstep) {
        size_t rowbase = ((size_t)(t * 4 + px) * 4 + bb) * 16 + coloff;
        s16x8 a0 = *(const s16x8*)&tb[term0    ][rowbase];
        s16x8 a1 = *(const s16x8*)&tb[term0 + 2][rowbase];

        f32x4 acc[4];
#pragma unroll
        for (int n = 0; n < 4; ++n) acc[n] = (f32x4){bz[n], bz[n], bz[n], bz[n]};
#pragma unroll
        for (int n = 0; n < 4; ++n)
            acc[n] = __builtin_amdgcn_mfma_f32_16x16x32_bf16(a0, wf[0][n], acc[n], 0, 0, 0);
#pragma unroll
        for (int n = 0; n < 4; ++n)
            acc[n] = __builtin_amdgcn_mfma_f32_16x16x32_bf16(a1, wf[1][n], acc[n], 0, 0, 0);

        // LayerNorm stats: rows = (pixel t*4+rr, batch g); cols span all 64.
        float s[4] = {0,0,0,0}, q[4] = {0,0,0,0};
#pragma unroll
        for (int n = 0; n < 4; ++n)
#pragma unroll
            for (int r = 0; r < 4; ++r) {
                float v = acc[n][r];
                s[r] += v; q[r] += v * v;
            }
#pragma unroll
        for (int msk = 1; msk < 16; msk <<= 1)
#pragma unroll
            for (int r = 0; r < 4; ++r) {
                s[r] += __shfl_xor(s[r], msk, 64);
                q[r] += __shfl_xor(q[r], msk, 64);
            }
        float mu[4], rs[4];
#pragma unroll
        for (int r = 0; r < 4; ++r) {
            mu[r] = s[r] * (1.f / 64.f);
            float var = q[r] * (1.f / 64.f) - mu[r] * mu[r];
            rs[r] = rsqrtf(var + EPS);
        }
        // pool over r (4 consecutive pixels), write pooled row (t, batch g)
        size_t ro = ((size_t)t * 4 + g) * 64;
#pragma unroll
        for (int n = 0; n < 4; ++n) {
            float pv = 0.f;
#pragma unroll
            for (int r = 0; r < 4; ++r) {
                float h = fmaf(gz[n] * rs[r], acc[n][r] - mu[r], tz[n]);
                pv += fmaxf(h, 0.f);
            }
            out[ro + n * 16 + c16] = f2b(pv * 0.25f);
        }
    }
}

// ---------------------------------------------------------------------------
// Stages 2/3 fused MM v2: wave owns an N-slice (COUT/4 cols) x all 64 rows
// -> 4m x WNF register blocking. LN stats cross-wave via LDS sq[64][4][2].
// POOL==4 (stage 2): out bf16 (P/4, B, COUT), rows = 16 pix x 4 batches,
//   in-register pooling over acc regs.
// POOL==1 (stage 3): rows flat (p*B+b); emits per-block colsums zblk
//   [blk][batch][COUT] fp32 (batch = reg index rr, reduce over m + g-shfl).
// ---------------------------------------------------------------------------
template <int CIN, int COUT, int POOL, int LOG2CIN>
__global__ __launch_bounds__(256)
void cheb_mm_v2_kernel(const unsigned short* __restrict__ t0,
                       const unsigned short* __restrict__ t1,
                       const unsigned short* __restrict__ t2,
                       const unsigned short* __restrict__ t3,
                       const unsigned short* __restrict__ Wt,
                       const float* __restrict__ bias,
                       const float* __restrict__ gam,
                       const float* __restrict__ bet,
                       void* __restrict__ outv)
{
    constexpr int KC   = 4 * CIN;
    constexpr int WNF  = COUT / 64;   // n-frags per wave
    constexpr int NKCH = KC / 64;
    constexpr int LDA  = 72;

    __shared__ unsigned short As[64 * LDA];
    __shared__ unsigned short Ws[COUT * LDA];
    __shared__ float sq[64][4][2];

    const int tid  = threadIdx.x;
    const int wave = tid >> 6;
    const int lane = tid & 63;
    const int g    = lane >> 4;
    const int c16  = lane & 15;
    const int wcol = wave * (COUT / 4);

    const unsigned short* tb[4] = { t0, t1, t2, t3 };

    float bz[WNF], gz[WNF], tz[WNF];
#pragma unroll
    for (int n = 0; n < WNF; ++n) {
        bz[n] = bias[wcol + n * 16 + c16];
        gz[n] = gam [wcol + n * 16 + c16];
        tz[n] = bet [wcol + n * 16 + c16];
    }

    f32x4 acc[4][WNF];
#pragma unroll
    for (int m = 0; m < 4; ++m)
#pragma unroll
        for (int n = 0; n < WNF; ++n)
            acc[m][n] = (f32x4){bz[n], bz[n], bz[n], bz[n]};

    for (int kc = 0; kc < NKCH; ++kc) {
        if (kc) __syncthreads();
        // ---- stage A: 64 rows x 64 k ----
#pragma unroll
        for (int i = tid; i < 64 * 8; i += 256) {
            int row = i >> 3, v = i & 7;
            int k = kc * 64 + v * 8;
            int term = k >> LOG2CIN;
            int c = k & (CIN - 1);
            size_t srow;
            if constexpr (POOL == 4) {
                int pix = blockIdx.x * 16 + ((row >> 4) << 2) + (row & 3);
                int rb  = (row >> 2) & 3;
                srow = ((size_t)pix * B + rb) * CIN + c;
            } else {
                srow = ((size_t)(blockIdx.x * 64 + row)) * CIN + c;
            }
            *(uint4*)&As[row * LDA + v * 8] = *(const uint4*)&tb[term][srow];
        }
        // ---- stage W: COUT rows x 64 k ----
#pragma unroll
        for (int i = tid; i < COUT * 8; i += 256) {
            int co = i >> 3, v = i & 7;
            *(uint4*)&Ws[co * LDA + v * 8] =
                *(const uint4*)&Wt[(size_t)co * KC + kc * 64 + v * 8];
        }
        __syncthreads();
        // ---- MFMA: 2 K-steps, 4m x WNF ----
#pragma unroll
        for (int ks = 0; ks < 2; ++ks) {
            s16x8 a[4];
#pragma unroll
            for (int m = 0; m < 4; ++m)
                a[m] = *(const s16x8*)&As[(m * 16 + c16) * LDA + ks * 32 + g * 8];
#pragma unroll
            for (int n = 0; n < WNF; ++n) {
                s16x8 bf = *(const s16x8*)&Ws[(wcol + n * 16 + c16) * LDA + ks * 32 + g * 8];
#pragma unroll
                for (int m = 0; m < 4; ++m)
                    acc[m][n] = __builtin_amdgcn_mfma_f32_16x16x32_bf16(a[m], bf, acc[m][n], 0, 0, 0);
            }
        }
    }

    // ---- LN stats: wave-partial per row, then cross-wave via LDS ----
    float sm[4][4], qm[4][4];
#pragma unroll
    for (int m = 0; m < 4; ++m)
#pragma unroll
        for (int r = 0; r < 4; ++r) { sm[m][r] = 0.f; qm[m][r] = 0.f; }
#pragma unroll
    for (int m = 0; m < 4; ++m)
#pragma unroll
        for (int n = 0; n < WNF; ++n)
#pragma unroll
            for (int r = 0; r < 4; ++r) {
                float v = acc[m][n][r];
                sm[m][r] += v; qm[m][r] += v * v;
            }
#pragma unroll
    for (int msk = 1; msk < 16; msk <<= 1)
#pragma unroll
        for (int m = 0; m < 4; ++m)
#pragma unroll
            for (int r = 0; r < 4; ++r) {
                sm[m][r] += __shfl_xor(sm[m][r], msk, 64);
                qm[m][r] += __shfl_xor(qm[m][r], msk, 64);
            }
    __syncthreads();   // protect As/Ws reuse boundary & order sq writes
    if (c16 == 0) {
#pragma unroll
        for (int m = 0; m < 4; ++m)
#pragma unroll
            for (int r = 0; r < 4; ++r) {
                sq[m * 16 + g * 4 + r][wave][0] = sm[m][r];
                sq[m * 16 + g * 4 + r][wave][1] = qm[m][r];
            }
    }
    __syncthreads();
    float mu[4][4], rs[4][4];
#pragma unroll
    for (int m = 0; m < 4; ++m)
#pragma unroll
        for (int r = 0; r < 4; ++r) {
            int row = m * 16 + g * 4 + r;
            float ss = sq[row][0][0] + sq[row][1][0] + sq[row][2][0] + sq[row][3][0];
            float qq = sq[row][0][1] + sq[row][1][1] + sq[row][2][1] + sq[row][3][1];
            mu[m][r] = ss * (1.f / COUT);
            float var = qq * (1.f / COUT) - mu[m][r] * mu[m][r];
            rs[m][r] = rsqrtf(var + EPS);
        }

    if constexpr (POOL == 4) {
        unsigned short* out = (unsigned short*)outv;
#pragma unroll
        for (int m = 0; m < 4; ++m) {
            size_t ro = ((size_t)(blockIdx.x * 4 + m) * B + g) * COUT + wcol;
#pragma unroll
            for (int n = 0; n < WNF; ++n) {
                float pv = 0.f;
#pragma unroll
                for (int r = 0; r < 4; ++r) {
                    float h = fmaf(gz[n] * rs[m][r], acc[m][n][r] - mu[m][r], tz[n]);
                    pv += fmaxf(h, 0.f);
                }
                out[ro + n * 16 + c16] = f2b(pv * 0.25f);
            }
        }
    } else {
        // colsum: batch of flat row = rr; sum over m in-reg, over g via shfl.
        float part[WNF][4];
#pragma unroll
        for (int n = 0; n < WNF; ++n)
#pragma unroll
            for (int r = 0; r < 4; ++r) part[n][r] = 0.f;
#pragma unroll
        for (int m = 0; m < 4; ++m)
#pragma unroll
            for (int n = 0; n < WNF; ++n)
#pragma unroll
                for (int r = 0; r < 4; ++r) {
                    float h = fmaf(gz[n] * rs[m][r], acc[m][n][r] - mu[m][r], tz[n]);
                    part[n][r] += fmaxf(h, 0.f);
                }
#pragma unroll
        for (int n = 0; n < WNF; ++n)
#pragma unroll
            for (int r = 0; r < 4; ++r) {
                part[n][r] += __shfl_xor(part[n][r], 16, 64);
                part[n][r] += __shfl_xor(part[n][r], 32, 64);
            }
        if (g == 0) {
            float* zb = (float*)outv + (size_t)blockIdx.x * B * COUT;
#pragma unroll
            for (int n = 0; n < WNF; ++n)
#pragma unroll
                for (int r = 0; r < 4; ++r)
                    zb[(size_t)r * COUT + wcol + n * 16 + c16] = part[n][r];
        }
    }
}

// ---------------------------------------------------------------------------
// Head: z[b] = (sum over 768 block-partials)/P2; relu(z@mW1+mb1)@mW2+mb2.
// ---------------------------------------------------------------------------
__global__ __launch_bounds__(512)
void head_kernel(const float* __restrict__ zblk,
                 const float* __restrict__ mW1, const float* __restrict__ mb1,
                 const float* __restrict__ mW2, const float* __restrict__ mb2,
                 float* __restrict__ out)
{
    __shared__ float zs[256];
    __shared__ float hsh[512];
    int b = blockIdx.x, tid = threadIdx.x;
    if (tid < 256) {
        float s = 0.f;
        for (int blk = 0; blk < NBLK3; ++blk)
            s += zblk[(size_t)blk * B * 256 + (size_t)b * 256 + tid];
        zs[tid] = s * (1.0f / P2);
    }
    __syncthreads();
    {
        float a = mb1[tid];
#pragma unroll 8
        for (int i = 0; i < 256; ++i) a = fmaf(zs[i], mW1[i * 512 + tid], a);
        hsh[tid] = fmaxf(a, 0.f);
    }
    __syncthreads();
    if (tid < 256) {
        float a = mb2[tid];
#pragma unroll 8
        for (int i = 0; i < 512; ++i) a = fmaf(hsh[i], mW2[i * 256 + tid], a);
        out[(size_t)b * 256 + tid] = a;
    }
}

} // anonymous namespace

extern "C" void kernel_launch(void* const* d_in, const int* in_sizes, int n_in,
                              void* d_out, int out_size, void* d_ws, size_t ws_size,
                              hipStream_t stream)
{
    const float* x     = (const float*)d_in[0];
    const int*   cols1 = (const int*)  d_in[1];
    const float* vals1 = (const float*)d_in[2];
    const int*   cols2 = (const int*)  d_in[3];
    const float* vals2 = (const float*)d_in[4];
    const int*   cols3 = (const int*)  d_in[5];
    const float* vals3 = (const float*)d_in[6];
    const float* W1  = (const float*)d_in[7];
    const float* b1  = (const float*)d_in[8];
    const float* g1  = (const float*)d_in[9];
    const float* bt1 = (const float*)d_in[10];
    const float* W2  = (const float*)d_in[11];
    const float* b2  = (const float*)d_in[12];
    const float* g2  = (const float*)d_in[13];
    const float* bt2 = (const float*)d_in[14];
    const float* W3  = (const float*)d_in[15];
    const float* b3  = (const float*)d_in[16];
    const float* g3  = (const float*)d_in[17];
    const float* bt3 = (const float*)d_in[18];
    const float* mW1 = (const float*)d_in[19];
    const float* mb1 = (const float*)d_in[20];
    const float* mW2 = (const float*)d_in[21];
    const float* mb2 = (const float*)d_in[22];
    float* out = (float*)d_out;

    // ---- workspace layout (256B-aligned slots) ----
    char* w = (char*)d_ws;
    size_t off = 0;
    auto alloc = [&](size_t bytes) -> void* {
        void* p = w + off;
        off += (bytes + 255) & ~(size_t)255;
        return p;
    };
    const size_t E1 = (size_t)B * P0 * 16;   // 12,582,912 elems
    unsigned short* xb  = (unsigned short*)alloc(E1 * 2);        // (P0,B,16)
    unsigned short* t_a = (unsigned short*)alloc(E1 * 2);
    unsigned short* t_b = (unsigned short*)alloc(E1 * 2);
    unsigned short* t_c = (unsigned short*)alloc(E1 * 2);
    unsigned short* h1  = (unsigned short*)alloc((size_t)P1 * B * 64 * 2);   // (P1,B,64)
    unsigned short* h2  = (unsigned short*)alloc((size_t)P2 * B * 128 * 2);  // (P2,B,128)
    unsigned short* Wt1 = (unsigned short*)alloc(64 * 64 * 2);
    unsigned short* Wt2 = (unsigned short*)alloc(256 * 128 * 2);
    unsigned short* Wt3 = (unsigned short*)alloc(512 * 256 * 2);
    float*          zblk = (float*)alloc((size_t)NBLK3 * B * 256 * 4);       // 3.1 MB

    // ---- precompute: layout transpose + bf16 weights ----
    x2p_kernel<<<(int)(((long)P0 * B * 2 + 255) / 256), 256, 0, stream>>>(x, xb);
    wt_all_kernel<<<(4096 + 32768 + 131072 + 255) / 256, 256, 0, stream>>>(
        W1, W2, W3, Wt1, Wt2, Wt3);

    // ---- Stage 1: P0, 16 -> 64, pool 4 ----
    {
        int Cv8 = B * 16 / 8;   // 8
        long tot = (long)P0 * Cv8;
        int nb = (int)((tot + 255) / 256);
        lmul_bf16_kernel<<<nb, 256, 0, stream>>>(xb,  nullptr, cols1, vals1, t_a, P0, Cv8, 1.f,  0.f);
        lmul_bf16_kernel<<<nb, 256, 0, stream>>>(t_a, xb,      cols1, vals1, t_b, P0, Cv8, 2.f, -1.f);
        lmul_bf16_kernel<<<nb, 256, 0, stream>>>(t_b, t_a,     cols1, vals1, t_c, P0, Cv8, 2.f, -1.f);
        s1_mm_kernel<<<2048, 256, 0, stream>>>(xb, t_a, t_b, t_c, Wt1, b1, g1, bt1, h1);
    }
    // ---- Stage 2: P1, 64 -> 128, pool 4 ----
    {
        int Cv8 = B * 64 / 8;   // 32
        long tot = (long)P1 * Cv8;
        int nb = (int)((tot + 255) / 256);
        lmul_bf16_kernel<<<nb, 256, 0, stream>>>(h1,  nullptr, cols2, vals2, t_a, P1, Cv8, 1.f,  0.f);
        lmul_bf16_kernel<<<nb, 256, 0, stream>>>(t_a, h1,      cols2, vals2, t_b, P1, Cv8, 2.f, -1.f);
        lmul_bf16_kernel<<<nb, 256, 0, stream>>>(t_b, t_a,     cols2, vals2, t_c, P1, Cv8, 2.f, -1.f);
        cheb_mm_v2_kernel<64, 128, 4, 6><<<(P1 * B) / 64, 256, 0, stream>>>(
            h1, t_a, t_b, t_c, Wt2, b2, g2, bt2, h2);
    }
    // ---- Stage 3: P2, 128 -> 256, no pool; emits colsum partials ----
    {
        int Cv8 = B * 128 / 8;  // 64
        long tot = (long)P2 * Cv8;
        int nb = (int)((tot + 255) / 256);
        lmul_bf16_kernel<<<nb, 256, 0, stream>>>(h2,  nullptr, cols3, vals3, t_a, P2, Cv8, 1.f,  0.f);
        lmul_bf16_kernel<<<nb, 256, 0, stream>>>(t_a, h2,      cols3, vals3, t_b, P2, Cv8, 2.f, -1.f);
        lmul_bf16_kernel<<<nb, 256, 0, stream>>>(t_b, t_a,     cols3, vals3, t_c, P2, Cv8, 2.f, -1.f);
        cheb_mm_v2_kernel<128, 256, 1, 7><<<NBLK3, 256, 0, stream>>>(
            h2, t_a, t_b, t_c, Wt3, b3, g3, bt3, zblk);
    }
    // ---- Head ----
    head_kernel<<<B, 512, 0, stream>>>(zblk, mW1, mb1, mW2, mb2, out);

    (void)in_sizes; (void)n_in; (void)out_size; (void)ws_size;
}

// Round 5
// 438.803 us; speedup vs baseline: 5.4125x; 1.0479x over previous
//
#include <hip/hip_runtime.h>
#include <hip/hip_bf16.h>

namespace {

constexpr int B  = 4;
constexpr int P0 = 196608, P1 = 49152, P2 = 12288;
constexpr int DEG = 8;
constexpr float EPS = 1e-5f;
constexpr int NBLK3 = (P2 * B) / 64;   // 768 stage-3 blocks -> zblk partials
constexpr int RSL = 16;                // zred slices
constexpr int RPB = NBLK3 / RSL;       // 48 zblk rows per slice

typedef __attribute__((ext_vector_type(4))) float f32x4;
typedef __attribute__((ext_vector_type(8))) short s16x8;

__device__ __forceinline__ float b2f(unsigned short u) {
    union { unsigned int i; float f; } c; c.i = (unsigned int)u << 16; return c.f;
}
__device__ __forceinline__ unsigned short f2b(float f) {
    __hip_bfloat16 h = __float2bfloat16(f);   // RNE
    return *reinterpret_cast<unsigned short*>(&h);
}

// ---------------------------------------------------------------------------
// x: (B,P0,16) fp32  ->  xb: (P0,B,16) bf16
// ---------------------------------------------------------------------------
__global__ __launch_bounds__(256)
void x2p_kernel(const float* __restrict__ in, unsigned short* __restrict__ out)
{
    long idx = (long)blockIdx.x * blockDim.x + threadIdx.x;   // P0*B*2 total
    if (idx >= (long)P0 * B * 2) return;
    int  h = (int)(idx & 1);
    int  b = (int)((idx >> 1) & 3);
    long p = idx >> 3;
    const float* src = in + ((size_t)b * P0 + p) * 16 + h * 8;
    float4 v0 = *(const float4*)src;
    float4 v1 = *(const float4*)(src + 4);
    union { uint4 u; unsigned short s[8]; } o;
    o.s[0] = f2b(v0.x); o.s[1] = f2b(v0.y); o.s[2] = f2b(v0.z); o.s[3] = f2b(v0.w);
    o.s[4] = f2b(v1.x); o.s[5] = f2b(v1.y); o.s[6] = f2b(v1.z); o.s[7] = f2b(v1.w);
    *(uint4*)&out[((size_t)p * B + b) * 16 + h * 8] = o.u;
}

// ---------------------------------------------------------------------------
// All three W (K,N) fp32 -> Wt (N,K) bf16 in one launch.
// ---------------------------------------------------------------------------
__global__ __launch_bounds__(256)
void wt_all_kernel(const float* __restrict__ W1, const float* __restrict__ W2,
                   const float* __restrict__ W3,
                   unsigned short* __restrict__ Wt1, unsigned short* __restrict__ Wt2,
                   unsigned short* __restrict__ Wt3)
{
    int i = blockIdx.x * 256 + threadIdx.x;
    if (i < 4096) {                       // W1: 64x64
        int n = i % 64, k = i / 64;
        Wt1[n * 64 + k] = f2b(W1[i]);
    } else if (i < 4096 + 32768) {        // W2: 256x128
        int j = i - 4096;
        int n = j % 128, k = j / 128;
        Wt2[n * 256 + k] = f2b(W2[j]);
    } else if (i < 4096 + 32768 + 131072) {  // W3: 512x256
        int j = i - 36864;
        int n = j % 256, k = j / 256;
        Wt3[n * 512 + k] = f2b(W3[j]);
    }
}

// ---------------------------------------------------------------------------
// Sparse Chebyshev step on (P, B*C) bf16 rows, fp32 accum. Taps (cols/vals)
// staged in LDS once per block (was: every thread of a row re-read all 64B
// of tap metadata -> up to 4x redundant L2 traffic). CV8 = B*C/16.
// ---------------------------------------------------------------------------
template <int CV8>
__global__ __launch_bounds__(256)
void lmul_v2_kernel(const unsigned short* __restrict__ in,
                    const unsigned short* __restrict__ prev,
                    const int* __restrict__ cols, const float* __restrict__ vals,
                    unsigned short* __restrict__ out,
                    float alpha, float beta)
{
    constexpr int ROWS = 256 / CV8;
    __shared__ int   cs[ROWS * DEG];
    __shared__ float vs[ROWS * DEG];
    const int tid = threadIdx.x;
    const long r0 = (long)blockIdx.x * ROWS;
    if (tid < ROWS * DEG) {                   // ROWS*DEG <= 256
        cs[tid] = cols[r0 * DEG + tid];
        vs[tid] = vals[r0 * DEG + tid];
    }
    __syncthreads();

    const int v  = tid & (CV8 - 1);
    const int lr = tid / CV8;
    const uint4* in16 = (const uint4*)in;

    float acc[8] = {0.f,0.f,0.f,0.f,0.f,0.f,0.f,0.f};
#pragma unroll
    for (int d = 0; d < DEG; ++d) {
        int   col = cs[lr * DEG + d];
        float w   = vs[lr * DEG + d];
        union { uint4 u; unsigned short s[8]; } x;
        x.u = in16[(size_t)col * CV8 + v];
#pragma unroll
        for (int j = 0; j < 8; ++j) acc[j] = fmaf(w, b2f(x.s[j]), acc[j]);
    }
    size_t o = (size_t)(r0 + lr) * CV8 + v;
    if (beta != 0.f) {
        union { uint4 u; unsigned short s[8]; } pv;
        pv.u = ((const uint4*)prev)[o];
#pragma unroll
        for (int j = 0; j < 8; ++j)
            acc[j] = fmaf(alpha, acc[j], beta * b2f(pv.s[j]));
    } else if (alpha != 1.f) {
#pragma unroll
        for (int j = 0; j < 8; ++j) acc[j] *= alpha;
    }
    union { uint4 u; unsigned short s[8]; } ou;
#pragma unroll
    for (int j = 0; j < 8; ++j) ou.s[j] = f2b(acc[j]);
    ((uint4*)out)[o] = ou.u;
}

// ---------------------------------------------------------------------------
// Stage-1 fused MM: KC=64, COUT=64, pool 4. W resident in registers,
// A-fragments read directly from global; grid-stride over 16-row wave-tiles.
// ---------------------------------------------------------------------------
__global__ __launch_bounds__(256)
void s1_mm_kernel(const unsigned short* __restrict__ t0,
                  const unsigned short* __restrict__ t1,
                  const unsigned short* __restrict__ t2,
                  const unsigned short* __restrict__ t3,
                  const unsigned short* __restrict__ Wt,
                  const float* __restrict__ bias,
                  const float* __restrict__ gam,
                  const float* __restrict__ bet,
                  unsigned short* __restrict__ out)
{
    const int wave = threadIdx.x >> 6;
    const int lane = threadIdx.x & 63;
    const int g    = lane >> 4;
    const int c16  = lane & 15;

    s16x8 wf[2][4];
#pragma unroll
    for (int ks = 0; ks < 2; ++ks)
#pragma unroll
        for (int n = 0; n < 4; ++n)
            wf[ks][n] = *(const s16x8*)&Wt[(size_t)(n * 16 + c16) * 64 + ks * 32 + g * 8];

    float bz[4], gz[4], tz[4];
#pragma unroll
    for (int n = 0; n < 4; ++n) {
        bz[n] = bias[n * 16 + c16];
        gz[n] = gam [n * 16 + c16];
        tz[n] = bet [n * 16 + c16];
    }

    const unsigned short* tb[4] = { t0, t1, t2, t3 };
    const int term0  = g >> 1;
    const int coloff = (g & 1) * 8;
    const int bb     = c16 >> 2;
    const int px     = c16 & 3;

    constexpr int NT = P0 / 4;
    const int wg     = blockIdx.x * 4 + wave;
    const int wstep  = gridDim.x * 4;

    for (int t = wg; t < NT; t += wstep) {
        size_t rowbase = ((size_t)(t * 4 + px) * 4 + bb) * 16 + coloff;
        s16x8 a0 = *(const s16x8*)&tb[term0    ][rowbase];
        s16x8 a1 = *(const s16x8*)&tb[term0 + 2][rowbase];

        f32x4 acc[4];
#pragma unroll
        for (int n = 0; n < 4; ++n) acc[n] = (f32x4){bz[n], bz[n], bz[n], bz[n]};
#pragma unroll
        for (int n = 0; n < 4; ++n)
            acc[n] = __builtin_amdgcn_mfma_f32_16x16x32_bf16(a0, wf[0][n], acc[n], 0, 0, 0);
#pragma unroll
        for (int n = 0; n < 4; ++n)
            acc[n] = __builtin_amdgcn_mfma_f32_16x16x32_bf16(a1, wf[1][n], acc[n], 0, 0, 0);

        float s[4] = {0,0,0,0}, q[4] = {0,0,0,0};
#pragma unroll
        for (int n = 0; n < 4; ++n)
#pragma unroll
            for (int r = 0; r < 4; ++r) {
                float v = acc[n][r];
                s[r] += v; q[r] += v * v;
            }
#pragma unroll
        for (int msk = 1; msk < 16; msk <<= 1)
#pragma unroll
            for (int r = 0; r < 4; ++r) {
                s[r] += __shfl_xor(s[r], msk, 64);
                q[r] += __shfl_xor(q[r], msk, 64);
            }
        float mu[4], rs[4];
#pragma unroll
        for (int r = 0; r < 4; ++r) {
            mu[r] = s[r] * (1.f / 64.f);
            float var = q[r] * (1.f / 64.f) - mu[r] * mu[r];
            rs[r] = rsqrtf(var + EPS);
        }
        size_t ro = ((size_t)t * 4 + g) * 64;
#pragma unroll
        for (int n = 0; n < 4; ++n) {
            float pv = 0.f;
#pragma unroll
            for (int r = 0; r < 4; ++r) {
                float h = fmaf(gz[n] * rs[r], acc[n][r] - mu[r], tz[n]);
                pv += fmaxf(h, 0.f);
            }
            out[ro + n * 16 + c16] = f2b(pv * 0.25f);
        }
    }
}

// ---------------------------------------------------------------------------
// Stages 2/3 fused MM v2 (unchanged from round 3).
// ---------------------------------------------------------------------------
template <int CIN, int COUT, int POOL, int LOG2CIN>
__global__ __launch_bounds__(256)
void cheb_mm_v2_kernel(const unsigned short* __restrict__ t0,
                       const unsigned short* __restrict__ t1,
                       const unsigned short* __restrict__ t2,
                       const unsigned short* __restrict__ t3,
                       const unsigned short* __restrict__ Wt,
                       const float* __restrict__ bias,
                       const float* __restrict__ gam,
                       const float* __restrict__ bet,
                       void* __restrict__ outv)
{
    constexpr int KC   = 4 * CIN;
    constexpr int WNF  = COUT / 64;
    constexpr int NKCH = KC / 64;
    constexpr int LDA  = 72;

    __shared__ unsigned short As[64 * LDA];
    __shared__ unsigned short Ws[COUT * LDA];
    __shared__ float sq[64][4][2];

    const int tid  = threadIdx.x;
    const int wave = tid >> 6;
    const int lane = tid & 63;
    const int g    = lane >> 4;
    const int c16  = lane & 15;
    const int wcol = wave * (COUT / 4);

    const unsigned short* tb[4] = { t0, t1, t2, t3 };

    float bz[WNF], gz[WNF], tz[WNF];
#pragma unroll
    for (int n = 0; n < WNF; ++n) {
        bz[n] = bias[wcol + n * 16 + c16];
        gz[n] = gam [wcol + n * 16 + c16];
        tz[n] = bet [wcol + n * 16 + c16];
    }

    f32x4 acc[4][WNF];
#pragma unroll
    for (int m = 0; m < 4; ++m)
#pragma unroll
        for (int n = 0; n < WNF; ++n)
            acc[m][n] = (f32x4){bz[n], bz[n], bz[n], bz[n]};

    for (int kc = 0; kc < NKCH; ++kc) {
        if (kc) __syncthreads();
#pragma unroll
        for (int i = tid; i < 64 * 8; i += 256) {
            int row = i >> 3, v = i & 7;
            int k = kc * 64 + v * 8;
            int term = k >> LOG2CIN;
            int c = k & (CIN - 1);
            size_t srow;
            if constexpr (POOL == 4) {
                int pix = blockIdx.x * 16 + ((row >> 4) << 2) + (row & 3);
                int rb  = (row >> 2) & 3;
                srow = ((size_t)pix * B + rb) * CIN + c;
            } else {
                srow = ((size_t)(blockIdx.x * 64 + row)) * CIN + c;
            }
            *(uint4*)&As[row * LDA + v * 8] = *(const uint4*)&tb[term][srow];
        }
#pragma unroll
        for (int i = tid; i < COUT * 8; i += 256) {
            int co = i >> 3, v = i & 7;
            *(uint4*)&Ws[co * LDA + v * 8] =
                *(const uint4*)&Wt[(size_t)co * KC + kc * 64 + v * 8];
        }
        __syncthreads();
#pragma unroll
        for (int ks = 0; ks < 2; ++ks) {
            s16x8 a[4];
#pragma unroll
            for (int m = 0; m < 4; ++m)
                a[m] = *(const s16x8*)&As[(m * 16 + c16) * LDA + ks * 32 + g * 8];
#pragma unroll
            for (int n = 0; n < WNF; ++n) {
                s16x8 bf = *(const s16x8*)&Ws[(wcol + n * 16 + c16) * LDA + ks * 32 + g * 8];
#pragma unroll
                for (int m = 0; m < 4; ++m)
                    acc[m][n] = __builtin_amdgcn_mfma_f32_16x16x32_bf16(a[m], bf, acc[m][n], 0, 0, 0);
            }
        }
    }

    float sm[4][4], qm[4][4];
#pragma unroll
    for (int m = 0; m < 4; ++m)
#pragma unroll
        for (int r = 0; r < 4; ++r) { sm[m][r] = 0.f; qm[m][r] = 0.f; }
#pragma unroll
    for (int m = 0; m < 4; ++m)
#pragma unroll
        for (int n = 0; n < WNF; ++n)
#pragma unroll
            for (int r = 0; r < 4; ++r) {
                float v = acc[m][n][r];
                sm[m][r] += v; qm[m][r] += v * v;
            }
#pragma unroll
    for (int msk = 1; msk < 16; msk <<= 1)
#pragma unroll
        for (int m = 0; m < 4; ++m)
#pragma unroll
            for (int r = 0; r < 4; ++r) {
                sm[m][r] += __shfl_xor(sm[m][r], msk, 64);
                qm[m][r] += __shfl_xor(qm[m][r], msk, 64);
            }
    __syncthreads();
    if (c16 == 0) {
#pragma unroll
        for (int m = 0; m < 4; ++m)
#pragma unroll
            for (int r = 0; r < 4; ++r) {
                sq[m * 16 + g * 4 + r][wave][0] = sm[m][r];
                sq[m * 16 + g * 4 + r][wave][1] = qm[m][r];
            }
    }
    __syncthreads();
    float mu[4][4], rs[4][4];
#pragma unroll
    for (int m = 0; m < 4; ++m)
#pragma unroll
        for (int r = 0; r < 4; ++r) {
            int row = m * 16 + g * 4 + r;
            float ss = sq[row][0][0] + sq[row][1][0] + sq[row][2][0] + sq[row][3][0];
            float qq = sq[row][0][1] + sq[row][1][1] + sq[row][2][1] + sq[row][3][1];
            mu[m][r] = ss * (1.f / COUT);
            float var = qq * (1.f / COUT) - mu[m][r] * mu[m][r];
            rs[m][r] = rsqrtf(var + EPS);
        }

    if constexpr (POOL == 4) {
        unsigned short* out = (unsigned short*)outv;
#pragma unroll
        for (int m = 0; m < 4; ++m) {
            size_t ro = ((size_t)(blockIdx.x * 4 + m) * B + g) * COUT + wcol;
#pragma unroll
            for (int n = 0; n < WNF; ++n) {
                float pv = 0.f;
#pragma unroll
                for (int r = 0; r < 4; ++r) {
                    float h = fmaf(gz[n] * rs[m][r], acc[m][n][r] - mu[m][r], tz[n]);
                    pv += fmaxf(h, 0.f);
                }
                out[ro + n * 16 + c16] = f2b(pv * 0.25f);
            }
        }
    } else {
        float part[WNF][4];
#pragma unroll
        for (int n = 0; n < WNF; ++n)
#pragma unroll
            for (int r = 0; r < 4; ++r) part[n][r] = 0.f;
#pragma unroll
        for (int m = 0; m < 4; ++m)
#pragma unroll
            for (int n = 0; n < WNF; ++n)
#pragma unroll
                for (int r = 0; r < 4; ++r) {
                    float h = fmaf(gz[n] * rs[m][r], acc[m][n][r] - mu[m][r], tz[n]);
                    part[n][r] += fmaxf(h, 0.f);
                }
#pragma unroll
        for (int n = 0; n < WNF; ++n)
#pragma unroll
            for (int r = 0; r < 4; ++r) {
                part[n][r] += __shfl_xor(part[n][r], 16, 64);
                part[n][r] += __shfl_xor(part[n][r], 32, 64);
            }
        if (g == 0) {
            float* zb = (float*)outv + (size_t)blockIdx.x * B * COUT;
#pragma unroll
            for (int n = 0; n < WNF; ++n)
#pragma unroll
                for (int r = 0; r < 4; ++r)
                    zb[(size_t)r * COUT + wcol + n * 16 + c16] = part[n][r];
        }
    }
}

// ---------------------------------------------------------------------------
// zblk (768, B*256) -> zp2 (RSL, B*256): coalesced parallel column reduce.
// grid = RSL*4 blocks x 256 thr; block (s, colgroup).
// ---------------------------------------------------------------------------
__global__ __launch_bounds__(256)
void zred_kernel(const float* __restrict__ zblk, float* __restrict__ zp2)
{
    int s   = blockIdx.x >> 2;
    int col = (blockIdx.x & 3) * 256 + threadIdx.x;
    float acc = 0.f;
#pragma unroll 8
    for (int r = 0; r < RPB; ++r)
        acc += zblk[(size_t)(s * RPB + r) * (B * 256) + col];
    zp2[(size_t)s * (B * 256) + col] = acc;
}

// ---------------------------------------------------------------------------
// Head: z[b] = (sum over RSL slice-partials)/P2; relu(z@mW1+mb1)@mW2+mb2.
// ---------------------------------------------------------------------------
__global__ __launch_bounds__(512)
void head_kernel(const float* __restrict__ zp2,
                 const float* __restrict__ mW1, const float* __restrict__ mb1,
                 const float* __restrict__ mW2, const float* __restrict__ mb2,
                 float* __restrict__ out)
{
    __shared__ float zs[256];
    __shared__ float hsh[512];
    int b = blockIdx.x, tid = threadIdx.x;
    if (tid < 256) {
        float s = 0.f;
#pragma unroll
        for (int sl = 0; sl < RSL; ++sl)
            s += zp2[(size_t)sl * (B * 256) + b * 256 + tid];
        zs[tid] = s * (1.0f / P2);
    }
    __syncthreads();
    {
        float a = mb1[tid];
#pragma unroll 8
        for (int i = 0; i < 256; ++i) a = fmaf(zs[i], mW1[i * 512 + tid], a);
        hsh[tid] = fmaxf(a, 0.f);
    }
    __syncthreads();
    if (tid < 256) {
        float a = mb2[tid];
#pragma unroll 8
        for (int i = 0; i < 512; ++i) a = fmaf(hsh[i], mW2[i * 256 + tid], a);
        out[(size_t)b * 256 + tid] = a;
    }
}

} // anonymous namespace

extern "C" void kernel_launch(void* const* d_in, const int* in_sizes, int n_in,
                              void* d_out, int out_size, void* d_ws, size_t ws_size,
                              hipStream_t stream)
{
    const float* x     = (const float*)d_in[0];
    const int*   cols1 = (const int*)  d_in[1];
    const float* vals1 = (const float*)d_in[2];
    const int*   cols2 = (const int*)  d_in[3];
    const float* vals2 = (const float*)d_in[4];
    const int*   cols3 = (const int*)  d_in[5];
    const float* vals3 = (const float*)d_in[6];
    const float* W1  = (const float*)d_in[7];
    const float* b1  = (const float*)d_in[8];
    const float* g1  = (const float*)d_in[9];
    const float* bt1 = (const float*)d_in[10];
    const float* W2  = (const float*)d_in[11];
    const float* b2  = (const float*)d_in[12];
    const float* g2  = (const float*)d_in[13];
    const float* bt2 = (const float*)d_in[14];
    const float* W3  = (const float*)d_in[15];
    const float* b3  = (const float*)d_in[16];
    const float* g3  = (const float*)d_in[17];
    const float* bt3 = (const float*)d_in[18];
    const float* mW1 = (const float*)d_in[19];
    const float* mb1 = (const float*)d_in[20];
    const float* mW2 = (const float*)d_in[21];
    const float* mb2 = (const float*)d_in[22];
    float* out = (float*)d_out;

    // ---- workspace layout (256B-aligned slots) ----
    char* w = (char*)d_ws;
    size_t off = 0;
    auto alloc = [&](size_t bytes) -> void* {
        void* p = w + off;
        off += (bytes + 255) & ~(size_t)255;
        return p;
    };
    const size_t E1 = (size_t)B * P0 * 16;
    unsigned short* xb  = (unsigned short*)alloc(E1 * 2);        // (P0,B,16)
    unsigned short* t_a = (unsigned short*)alloc(E1 * 2);
    unsigned short* t_b = (unsigned short*)alloc(E1 * 2);
    unsigned short* t_c = (unsigned short*)alloc(E1 * 2);
    unsigned short* h1  = (unsigned short*)alloc((size_t)P1 * B * 64 * 2);
    unsigned short* h2  = (unsigned short*)alloc((size_t)P2 * B * 128 * 2);
    unsigned short* Wt1 = (unsigned short*)alloc(64 * 64 * 2);
    unsigned short* Wt2 = (unsigned short*)alloc(256 * 128 * 2);
    unsigned short* Wt3 = (unsigned short*)alloc(512 * 256 * 2);
    float*          zblk = (float*)alloc((size_t)NBLK3 * B * 256 * 4);
    float*          zp2  = (float*)alloc((size_t)RSL * B * 256 * 4);

    // ---- precompute: layout transpose + bf16 weights ----
    x2p_kernel<<<(int)(((long)P0 * B * 2 + 255) / 256), 256, 0, stream>>>(x, xb);
    wt_all_kernel<<<(4096 + 32768 + 131072 + 255) / 256, 256, 0, stream>>>(
        W1, W2, W3, Wt1, Wt2, Wt3);

    // ---- Stage 1: P0, 16 -> 64, pool 4  (CV8 = 8, 32 rows/block) ----
    {
        lmul_v2_kernel<8><<<P0 / 32, 256, 0, stream>>>(xb,  nullptr, cols1, vals1, t_a, 1.f,  0.f);
        lmul_v2_kernel<8><<<P0 / 32, 256, 0, stream>>>(t_a, xb,      cols1, vals1, t_b, 2.f, -1.f);
        lmul_v2_kernel<8><<<P0 / 32, 256, 0, stream>>>(t_b, t_a,     cols1, vals1, t_c, 2.f, -1.f);
        s1_mm_kernel<<<2048, 256, 0, stream>>>(xb, t_a, t_b, t_c, Wt1, b1, g1, bt1, h1);
    }
    // ---- Stage 2: P1, 64 -> 128, pool 4  (CV8 = 32, 8 rows/block) ----
    {
        lmul_v2_kernel<32><<<P1 / 8, 256, 0, stream>>>(h1,  nullptr, cols2, vals2, t_a, 1.f,  0.f);
        lmul_v2_kernel<32><<<P1 / 8, 256, 0, stream>>>(t_a, h1,      cols2, vals2, t_b, 2.f, -1.f);
        lmul_v2_kernel<32><<<P1 / 8, 256, 0, stream>>>(t_b, t_a,     cols2, vals2, t_c, 2.f, -1.f);
        cheb_mm_v2_kernel<64, 128, 4, 6><<<(P1 * B) / 64, 256, 0, stream>>>(
            h1, t_a, t_b, t_c, Wt2, b2, g2, bt2, h2);
    }
    // ---- Stage 3: P2, 128 -> 256, no pool  (CV8 = 64, 4 rows/block) ----
    {
        lmul_v2_kernel<64><<<P2 / 4, 256, 0, stream>>>(h2,  nullptr, cols3, vals3, t_a, 1.f,  0.f);
        lmul_v2_kernel<64><<<P2 / 4, 256, 0, stream>>>(t_a, h2,      cols3, vals3, t_b, 2.f, -1.f);
        lmul_v2_kernel<64><<<P2 / 4, 256, 0, stream>>>(t_b, t_a,     cols3, vals3, t_c, 2.f, -1.f);
        cheb_mm_v2_kernel<128, 256, 1, 7><<<NBLK3, 256, 0, stream>>>(
            h2, t_a, t_b, t_c, Wt3, b3, g3, bt3, zblk);
    }
    // ---- z reduce + head ----
    zred_kernel<<<RSL * 4, 256, 0, stream>>>(zblk, zp2);
    head_kernel<<<B, 512, 0, stream>>>(zp2, mW1, mb1, mW2, mb2, out);

    (void)in_sizes; (void)n_in; (void)out_size; (void)ws_size;
}

// Round 6
// 420.913 us; speedup vs baseline: 5.6425x; 1.0425x over previous
//
#include <hip/hip_runtime.h>
#include <hip/hip_bf16.h>

namespace {

constexpr int B  = 4;
constexpr int P0 = 196608, P1 = 49152, P2 = 12288;
constexpr int DEG = 8;
constexpr float EPS = 1e-5f;
constexpr int NBLK3 = (P2 * B) / 64;   // 768 zblk partial rows (384 blocks x GM=2)
constexpr int RSL = 16;                // zred slices
constexpr int RPB = NBLK3 / RSL;       // 48 zblk rows per slice

typedef __attribute__((ext_vector_type(4))) float f32x4;
typedef __attribute__((ext_vector_type(8))) short s16x8;

__device__ __forceinline__ float b2f(unsigned short u) {
    union { unsigned int i; float f; } c; c.i = (unsigned int)u << 16; return c.f;
}
__device__ __forceinline__ unsigned short f2b(float f) {
    __hip_bfloat16 h = __float2bfloat16(f);   // RNE
    return *reinterpret_cast<unsigned short*>(&h);
}

// ---------------------------------------------------------------------------
// x: (B,P0,16) fp32  ->  xb: (P0,B,16) bf16
// ---------------------------------------------------------------------------
__global__ __launch_bounds__(256)
void x2p_kernel(const float* __restrict__ in, unsigned short* __restrict__ out)
{
    long idx = (long)blockIdx.x * blockDim.x + threadIdx.x;   // P0*B*2 total
    if (idx >= (long)P0 * B * 2) return;
    int  h = (int)(idx & 1);
    int  b = (int)((idx >> 1) & 3);
    long p = idx >> 3;
    const float* src = in + ((size_t)b * P0 + p) * 16 + h * 8;
    float4 v0 = *(const float4*)src;
    float4 v1 = *(const float4*)(src + 4);
    union { uint4 u; unsigned short s[8]; } o;
    o.s[0] = f2b(v0.x); o.s[1] = f2b(v0.y); o.s[2] = f2b(v0.z); o.s[3] = f2b(v0.w);
    o.s[4] = f2b(v1.x); o.s[5] = f2b(v1.y); o.s[6] = f2b(v1.z); o.s[7] = f2b(v1.w);
    *(uint4*)&out[((size_t)p * B + b) * 16 + h * 8] = o.u;
}

// ---------------------------------------------------------------------------
// All three W (K,N) fp32 -> Wt (N,K) bf16 in one launch.
// ---------------------------------------------------------------------------
__global__ __launch_bounds__(256)
void wt_all_kernel(const float* __restrict__ W1, const float* __restrict__ W2,
                   const float* __restrict__ W3,
                   unsigned short* __restrict__ Wt1, unsigned short* __restrict__ Wt2,
                   unsigned short* __restrict__ Wt3)
{
    int i = blockIdx.x * 256 + threadIdx.x;
    if (i < 4096) {                       // W1: 64x64
        int n = i % 64, k = i / 64;
        Wt1[n * 64 + k] = f2b(W1[i]);
    } else if (i < 4096 + 32768) {        // W2: 256x128
        int j = i - 4096;
        int n = j % 128, k = j / 128;
        Wt2[n * 256 + k] = f2b(W2[j]);
    } else if (i < 4096 + 32768 + 131072) {  // W3: 512x256
        int j = i - 36864;
        int n = j % 256, k = j / 256;
        Wt3[n * 512 + k] = f2b(W3[j]);
    }
}

// ---------------------------------------------------------------------------
// Sparse Chebyshev step on (P, B*C) bf16 rows, fp32 accum. Taps staged in LDS.
// ---------------------------------------------------------------------------
template <int CV8>
__global__ __launch_bounds__(256)
void lmul_v2_kernel(const unsigned short* __restrict__ in,
                    const unsigned short* __restrict__ prev,
                    const int* __restrict__ cols, const float* __restrict__ vals,
                    unsigned short* __restrict__ out,
                    float alpha, float beta)
{
    constexpr int ROWS = 256 / CV8;
    __shared__ int   cs[ROWS * DEG];
    __shared__ float vs[ROWS * DEG];
    const int tid = threadIdx.x;
    const long r0 = (long)blockIdx.x * ROWS;
    if (tid < ROWS * DEG) {
        cs[tid] = cols[r0 * DEG + tid];
        vs[tid] = vals[r0 * DEG + tid];
    }
    __syncthreads();

    const int v  = tid & (CV8 - 1);
    const int lr = tid / CV8;
    const uint4* in16 = (const uint4*)in;

    float acc[8] = {0.f,0.f,0.f,0.f,0.f,0.f,0.f,0.f};
#pragma unroll
    for (int d = 0; d < DEG; ++d) {
        int   col = cs[lr * DEG + d];
        float w   = vs[lr * DEG + d];
        union { uint4 u; unsigned short s[8]; } x;
        x.u = in16[(size_t)col * CV8 + v];
#pragma unroll
        for (int j = 0; j < 8; ++j) acc[j] = fmaf(w, b2f(x.s[j]), acc[j]);
    }
    size_t o = (size_t)(r0 + lr) * CV8 + v;
    if (beta != 0.f) {
        union { uint4 u; unsigned short s[8]; } pv;
        pv.u = ((const uint4*)prev)[o];
#pragma unroll
        for (int j = 0; j < 8; ++j)
            acc[j] = fmaf(alpha, acc[j], beta * b2f(pv.s[j]));
    } else if (alpha != 1.f) {
#pragma unroll
        for (int j = 0; j < 8; ++j) acc[j] *= alpha;
    }
    union { uint4 u; unsigned short s[8]; } ou;
#pragma unroll
    for (int j = 0; j < 8; ++j) ou.s[j] = f2b(acc[j]);
    ((uint4*)out)[o] = ou.u;
}

// ---------------------------------------------------------------------------
// Stage-1 fused MM: KC=64, COUT=64, pool 4. W resident in registers,
// A-fragments read directly from global; grid-stride over 16-row wave-tiles.
// ---------------------------------------------------------------------------
__global__ __launch_bounds__(256)
void s1_mm_kernel(const unsigned short* __restrict__ t0,
                  const unsigned short* __restrict__ t1,
                  const unsigned short* __restrict__ t2,
                  const unsigned short* __restrict__ t3,
                  const unsigned short* __restrict__ Wt,
                  const float* __restrict__ bias,
                  const float* __restrict__ gam,
                  const float* __restrict__ bet,
                  unsigned short* __restrict__ out)
{
    const int wave = threadIdx.x >> 6;
    const int lane = threadIdx.x & 63;
    const int g    = lane >> 4;
    const int c16  = lane & 15;

    s16x8 wf[2][4];
#pragma unroll
    for (int ks = 0; ks < 2; ++ks)
#pragma unroll
        for (int n = 0; n < 4; ++n)
            wf[ks][n] = *(const s16x8*)&Wt[(size_t)(n * 16 + c16) * 64 + ks * 32 + g * 8];

    float bz[4], gz[4], tz[4];
#pragma unroll
    for (int n = 0; n < 4; ++n) {
        bz[n] = bias[n * 16 + c16];
        gz[n] = gam [n * 16 + c16];
        tz[n] = bet [n * 16 + c16];
    }

    const unsigned short* tb[4] = { t0, t1, t2, t3 };
    const int term0  = g >> 1;
    const int coloff = (g & 1) * 8;
    const int bb     = c16 >> 2;
    const int px     = c16 & 3;

    constexpr int NT = P0 / 4;
    const int wg     = blockIdx.x * 4 + wave;
    const int wstep  = gridDim.x * 4;

    for (int t = wg; t < NT; t += wstep) {
        size_t rowbase = ((size_t)(t * 4 + px) * 4 + bb) * 16 + coloff;
        s16x8 a0 = *(const s16x8*)&tb[term0    ][rowbase];
        s16x8 a1 = *(const s16x8*)&tb[term0 + 2][rowbase];

        f32x4 acc[4];
#pragma unroll
        for (int n = 0; n < 4; ++n) acc[n] = (f32x4){bz[n], bz[n], bz[n], bz[n]};
#pragma unroll
        for (int n = 0; n < 4; ++n)
            acc[n] = __builtin_amdgcn_mfma_f32_16x16x32_bf16(a0, wf[0][n], acc[n], 0, 0, 0);
#pragma unroll
        for (int n = 0; n < 4; ++n)
            acc[n] = __builtin_amdgcn_mfma_f32_16x16x32_bf16(a1, wf[1][n], acc[n], 0, 0, 0);

        float s[4] = {0,0,0,0}, q[4] = {0,0,0,0};
#pragma unroll
        for (int n = 0; n < 4; ++n)
#pragma unroll
            for (int r = 0; r < 4; ++r) {
                float v = acc[n][r];
                s[r] += v; q[r] += v * v;
            }
#pragma unroll
        for (int msk = 1; msk < 16; msk <<= 1)
#pragma unroll
            for (int r = 0; r < 4; ++r) {
                s[r] += __shfl_xor(s[r], msk, 64);
                q[r] += __shfl_xor(q[r], msk, 64);
            }
        float mu[4], rs[4];
#pragma unroll
        for (int r = 0; r < 4; ++r) {
            mu[r] = s[r] * (1.f / 64.f);
            float var = q[r] * (1.f / 64.f) - mu[r] * mu[r];
            rs[r] = rsqrtf(var + EPS);
        }
        size_t ro = ((size_t)t * 4 + g) * 64;
#pragma unroll
        for (int n = 0; n < 4; ++n) {
            float pv = 0.f;
#pragma unroll
            for (int r = 0; r < 4; ++r) {
                float h = fmaf(gz[n] * rs[r], acc[n][r] - mu[r], tz[n]);
                pv += fmaxf(h, 0.f);
            }
            out[ro + n * 16 + c16] = f2b(pv * 0.25f);
        }
    }
}

// ---------------------------------------------------------------------------
// Stages 2/3 fused MM v3: 512 threads = 8 waves in GM x GN grid; each wave
// owns a 64x64 output tile (4m x 4n frags -> 32 MFMA per 16 ds_read_b128).
// LDS XOR-swizzled (T2): byte = row*128 + (cb ^ ((row&7)<<4)) -> the
// 16-distinct-row fragment read degrades from 8-way conflict to 2-way (free).
// LN stats cross-wave via sq[BM][GN][2].
// POOL==4: in-register 4:1 pixel pooling, bf16 out (P/4, B, COUT).
// POOL==1: per-(block,gm) column sums -> zblk[(blk*GM+gm)][batch][COUT].
// ---------------------------------------------------------------------------
template <int CIN, int COUT, int GM, int GN, int POOL, int LOG2CIN>
__global__ __launch_bounds__(512)
void cheb_mm_v3_kernel(const unsigned short* __restrict__ t0,
                       const unsigned short* __restrict__ t1,
                       const unsigned short* __restrict__ t2,
                       const unsigned short* __restrict__ t3,
                       const unsigned short* __restrict__ Wt,
                       const float* __restrict__ bias,
                       const float* __restrict__ gam,
                       const float* __restrict__ bet,
                       void* __restrict__ outv)
{
    constexpr int KC   = 4 * CIN;
    constexpr int BM   = GM * 64;
    constexpr int NKCH = KC / 64;

    __shared__ unsigned short As[BM * 64];     // swizzled, 128B/row
    __shared__ unsigned short Ws[COUT * 64];   // swizzled
    __shared__ float sq[BM][GN][2];

    const int tid  = threadIdx.x;
    const int wv   = tid >> 6;
    const int gm   = wv / GN;
    const int gn   = wv % GN;
    const int lane = tid & 63;
    const int g    = lane >> 4;
    const int c16  = lane & 15;

    const unsigned short* tb[4] = { t0, t1, t2, t3 };

    float bz[4], gz[4], tz[4];
#pragma unroll
    for (int n = 0; n < 4; ++n) {
        int col = gn * 64 + n * 16 + c16;
        bz[n] = bias[col]; gz[n] = gam[col]; tz[n] = bet[col];
    }

    f32x4 acc[4][4];
#pragma unroll
    for (int m = 0; m < 4; ++m)
#pragma unroll
        for (int n = 0; n < 4; ++n)
            acc[m][n] = (f32x4){bz[n], bz[n], bz[n], bz[n]};

    for (int kc = 0; kc < NKCH; ++kc) {
        if (kc) __syncthreads();
        // ---- stage A: BM rows x 64 k, swizzled ----
#pragma unroll
        for (int it = 0; it < BM * 8 / 512; ++it) {
            int i = tid + it * 512;
            int row = i >> 3, v = i & 7;
            int k = kc * 64 + v * 8;
            int term = k >> LOG2CIN;
            int c = k & (CIN - 1);
            size_t srow;
            if constexpr (POOL == 4) {
                int pix = blockIdx.x * (BM / 4) + ((row >> 4) << 2) + (row & 3);
                int rb  = (row >> 2) & 3;
                srow = ((size_t)pix * B + rb) * CIN + c;
            } else {
                srow = ((size_t)(blockIdx.x * BM + row)) * CIN + c;
            }
            *(uint4*)((char*)As + row * 128 + ((v * 16) ^ ((row & 7) << 4))) =
                *(const uint4*)&tb[term][srow];
        }
        // ---- stage W: COUT rows x 64 k, swizzled ----
#pragma unroll
        for (int it = 0; it < COUT * 8 / 512; ++it) {
            int i = tid + it * 512;
            int co = i >> 3, v = i & 7;
            *(uint4*)((char*)Ws + co * 128 + ((v * 16) ^ ((co & 7) << 4))) =
                *(const uint4*)&Wt[(size_t)co * KC + kc * 64 + v * 8];
        }
        __syncthreads();
        // ---- MFMA: 2 K-steps, 4m x 4n ----
#pragma unroll
        for (int ks = 0; ks < 2; ++ks) {
            const int cb  = ks * 64 + g * 16;
            const int swz = cb ^ ((c16 & 7) << 4);
            s16x8 a[4], bw[4];
#pragma unroll
            for (int m = 0; m < 4; ++m)
                a[m] = *(const s16x8*)((const char*)As + (gm * 64 + m * 16 + c16) * 128 + swz);
#pragma unroll
            for (int n = 0; n < 4; ++n)
                bw[n] = *(const s16x8*)((const char*)Ws + (gn * 64 + n * 16 + c16) * 128 + swz);
#pragma unroll
            for (int n = 0; n < 4; ++n)
#pragma unroll
                for (int m = 0; m < 4; ++m)
                    acc[m][n] = __builtin_amdgcn_mfma_f32_16x16x32_bf16(a[m], bw[n], acc[m][n], 0, 0, 0);
        }
    }

    // ---- LN stats: per-wave column-slice partials, cross-wave via sq ----
    float sm[4][4], qm[4][4];
#pragma unroll
    for (int m = 0; m < 4; ++m)
#pragma unroll
        for (int r = 0; r < 4; ++r) { sm[m][r] = 0.f; qm[m][r] = 0.f; }
#pragma unroll
    for (int m = 0; m < 4; ++m)
#pragma unroll
        for (int n = 0; n < 4; ++n)
#pragma unroll
            for (int r = 0; r < 4; ++r) {
                float v = acc[m][n][r];
                sm[m][r] += v; qm[m][r] += v * v;
            }
#pragma unroll
    for (int msk = 1; msk < 16; msk <<= 1)
#pragma unroll
        for (int m = 0; m < 4; ++m)
#pragma unroll
            for (int r = 0; r < 4; ++r) {
                sm[m][r] += __shfl_xor(sm[m][r], msk, 64);
                qm[m][r] += __shfl_xor(qm[m][r], msk, 64);
            }
    __syncthreads();   // all MFMA reads of As/Ws done; order sq publish
    if (c16 == 0) {
#pragma unroll
        for (int m = 0; m < 4; ++m)
#pragma unroll
            for (int r = 0; r < 4; ++r) {
                sq[gm * 64 + m * 16 + g * 4 + r][gn][0] = sm[m][r];
                sq[gm * 64 + m * 16 + g * 4 + r][gn][1] = qm[m][r];
            }
    }
    __syncthreads();
    float mu[4][4], rs[4][4];
#pragma unroll
    for (int m = 0; m < 4; ++m)
#pragma unroll
        for (int r = 0; r < 4; ++r) {
            int row = gm * 64 + m * 16 + g * 4 + r;
            float ss = 0.f, qq = 0.f;
#pragma unroll
            for (int j = 0; j < GN; ++j) { ss += sq[row][j][0]; qq += sq[row][j][1]; }
            mu[m][r] = ss * (1.f / COUT);
            float var = qq * (1.f / COUT) - mu[m][r] * mu[m][r];
            rs[m][r] = rsqrtf(var + EPS);
        }

    if constexpr (POOL == 4) {
        unsigned short* outp = (unsigned short*)outv;
#pragma unroll
        for (int m = 0; m < 4; ++m) {
            size_t ro = ((size_t)(blockIdx.x * (BM / 16) + gm * 4 + m) * B + g) * COUT + gn * 64;
#pragma unroll
            for (int n = 0; n < 4; ++n) {
                float pv = 0.f;
#pragma unroll
                for (int r = 0; r < 4; ++r) {
                    float h = fmaf(gz[n] * rs[m][r], acc[m][n][r] - mu[m][r], tz[n]);
                    pv += fmaxf(h, 0.f);
                }
                outp[ro + n * 16 + c16] = f2b(pv * 0.25f);
            }
        }
    } else {
        // rows are (p*B + b) flat; row offsets all ≡0 mod 4 -> batch = r.
        float part[4][4];   // [n][r]
#pragma unroll
        for (int n = 0; n < 4; ++n)
#pragma unroll
            for (int r = 0; r < 4; ++r) part[n][r] = 0.f;
#pragma unroll
        for (int m = 0; m < 4; ++m)
#pragma unroll
            for (int n = 0; n < 4; ++n)
#pragma unroll
                for (int r = 0; r < 4; ++r) {
                    float h = fmaf(gz[n] * rs[m][r], acc[m][n][r] - mu[m][r], tz[n]);
                    part[n][r] += fmaxf(h, 0.f);
                }
#pragma unroll
        for (int n = 0; n < 4; ++n)
#pragma unroll
            for (int r = 0; r < 4; ++r) {
                part[n][r] += __shfl_xor(part[n][r], 16, 64);
                part[n][r] += __shfl_xor(part[n][r], 32, 64);
            }
        if (g == 0) {
            float* zb = (float*)outv + ((size_t)(blockIdx.x * GM + gm)) * (B * COUT);
#pragma unroll
            for (int n = 0; n < 4; ++n)
#pragma unroll
                for (int r = 0; r < 4; ++r)
                    zb[(size_t)r * COUT + gn * 64 + n * 16 + c16] = part[n][r];
        }
    }
}

// ---------------------------------------------------------------------------
// zblk (768, B*256) -> zp2 (RSL, B*256): coalesced parallel column reduce.
// ---------------------------------------------------------------------------
__global__ __launch_bounds__(256)
void zred_kernel(const float* __restrict__ zblk, float* __restrict__ zp2)
{
    int s   = blockIdx.x >> 2;
    int col = (blockIdx.x & 3) * 256 + threadIdx.x;
    float acc = 0.f;
#pragma unroll 8
    for (int r = 0; r < RPB; ++r)
        acc += zblk[(size_t)(s * RPB + r) * (B * 256) + col];
    zp2[(size_t)s * (B * 256) + col] = acc;
}

// ---------------------------------------------------------------------------
// Head: z[b] = (sum over RSL slice-partials)/P2; relu(z@mW1+mb1)@mW2+mb2.
// ---------------------------------------------------------------------------
__global__ __launch_bounds__(512)
void head_kernel(const float* __restrict__ zp2,
                 const float* __restrict__ mW1, const float* __restrict__ mb1,
                 const float* __restrict__ mW2, const float* __restrict__ mb2,
                 float* __restrict__ out)
{
    __shared__ float zs[256];
    __shared__ float hsh[512];
    int b = blockIdx.x, tid = threadIdx.x;
    if (tid < 256) {
        float s = 0.f;
#pragma unroll
        for (int sl = 0; sl < RSL; ++sl)
            s += zp2[(size_t)sl * (B * 256) + b * 256 + tid];
        zs[tid] = s * (1.0f / P2);
    }
    __syncthreads();
    {
        float a = mb1[tid];
#pragma unroll 8
        for (int i = 0; i < 256; ++i) a = fmaf(zs[i], mW1[i * 512 + tid], a);
        hsh[tid] = fmaxf(a, 0.f);
    }
    __syncthreads();
    if (tid < 256) {
        float a = mb2[tid];
#pragma unroll 8
        for (int i = 0; i < 512; ++i) a = fmaf(hsh[i], mW2[i * 256 + tid], a);
        out[(size_t)b * 256 + tid] = a;
    }
}

} // anonymous namespace

extern "C" void kernel_launch(void* const* d_in, const int* in_sizes, int n_in,
                              void* d_out, int out_size, void* d_ws, size_t ws_size,
                              hipStream_t stream)
{
    const float* x     = (const float*)d_in[0];
    const int*   cols1 = (const int*)  d_in[1];
    const float* vals1 = (const float*)d_in[2];
    const int*   cols2 = (const int*)  d_in[3];
    const float* vals2 = (const float*)d_in[4];
    const int*   cols3 = (const int*)  d_in[5];
    const float* vals3 = (const float*)d_in[6];
    const float* W1  = (const float*)d_in[7];
    const float* b1  = (const float*)d_in[8];
    const float* g1  = (const float*)d_in[9];
    const float* bt1 = (const float*)d_in[10];
    const float* W2  = (const float*)d_in[11];
    const float* b2  = (const float*)d_in[12];
    const float* g2  = (const float*)d_in[13];
    const float* bt2 = (const float*)d_in[14];
    const float* W3  = (const float*)d_in[15];
    const float* b3  = (const float*)d_in[16];
    const float* g3  = (const float*)d_in[17];
    const float* bt3 = (const float*)d_in[18];
    const float* mW1 = (const float*)d_in[19];
    const float* mb1 = (const float*)d_in[20];
    const float* mW2 = (const float*)d_in[21];
    const float* mb2 = (const float*)d_in[22];
    float* out = (float*)d_out;

    // ---- workspace layout (256B-aligned slots) ----
    char* w = (char*)d_ws;
    size_t off = 0;
    auto alloc = [&](size_t bytes) -> void* {
        void* p = w + off;
        off += (bytes + 255) & ~(size_t)255;
        return p;
    };
    const size_t E1 = (size_t)B * P0 * 16;
    unsigned short* xb  = (unsigned short*)alloc(E1 * 2);        // (P0,B,16)
    unsigned short* t_a = (unsigned short*)alloc(E1 * 2);
    unsigned short* t_b = (unsigned short*)alloc(E1 * 2);
    unsigned short* t_c = (unsigned short*)alloc(E1 * 2);
    unsigned short* h1  = (unsigned short*)alloc((size_t)P1 * B * 64 * 2);
    unsigned short* h2  = (unsigned short*)alloc((size_t)P2 * B * 128 * 2);
    unsigned short* Wt1 = (unsigned short*)alloc(64 * 64 * 2);
    unsigned short* Wt2 = (unsigned short*)alloc(256 * 128 * 2);
    unsigned short* Wt3 = (unsigned short*)alloc(512 * 256 * 2);
    float*          zblk = (float*)alloc((size_t)NBLK3 * B * 256 * 4);
    float*          zp2  = (float*)alloc((size_t)RSL * B * 256 * 4);

    // ---- precompute: layout transpose + bf16 weights ----
    x2p_kernel<<<(int)(((long)P0 * B * 2 + 255) / 256), 256, 0, stream>>>(x, xb);
    wt_all_kernel<<<(4096 + 32768 + 131072 + 255) / 256, 256, 0, stream>>>(
        W1, W2, W3, Wt1, Wt2, Wt3);

    // ---- Stage 1: P0, 16 -> 64, pool 4 ----
    {
        lmul_v2_kernel<8><<<P0 / 32, 256, 0, stream>>>(xb,  nullptr, cols1, vals1, t_a, 1.f,  0.f);
        lmul_v2_kernel<8><<<P0 / 32, 256, 0, stream>>>(t_a, xb,      cols1, vals1, t_b, 2.f, -1.f);
        lmul_v2_kernel<8><<<P0 / 32, 256, 0, stream>>>(t_b, t_a,     cols1, vals1, t_c, 2.f, -1.f);
        s1_mm_kernel<<<2048, 256, 0, stream>>>(xb, t_a, t_b, t_c, Wt1, b1, g1, bt1, h1);
    }
    // ---- Stage 2: P1, 64 -> 128, pool 4 ----
    {
        lmul_v2_kernel<32><<<P1 / 8, 256, 0, stream>>>(h1,  nullptr, cols2, vals2, t_a, 1.f,  0.f);
        lmul_v2_kernel<32><<<P1 / 8, 256, 0, stream>>>(t_a, h1,      cols2, vals2, t_b, 2.f, -1.f);
        lmul_v2_kernel<32><<<P1 / 8, 256, 0, stream>>>(t_b, t_a,     cols2, vals2, t_c, 2.f, -1.f);
        // BM=256: (P1*B)/256 = 768 blocks
        cheb_mm_v3_kernel<64, 128, 4, 2, 4, 6><<<(P1 * B) / 256, 512, 0, stream>>>(
            h1, t_a, t_b, t_c, Wt2, b2, g2, bt2, h2);
    }
    // ---- Stage 3: P2, 128 -> 256, no pool; emits colsum partials ----
    {
        lmul_v2_kernel<64><<<P2 / 4, 256, 0, stream>>>(h2,  nullptr, cols3, vals3, t_a, 1.f,  0.f);
        lmul_v2_kernel<64><<<P2 / 4, 256, 0, stream>>>(t_a, h2,      cols3, vals3, t_b, 2.f, -1.f);
        lmul_v2_kernel<64><<<P2 / 4, 256, 0, stream>>>(t_b, t_a,     cols3, vals3, t_c, 2.f, -1.f);
        // BM=128: (P2*B)/128 = 384 blocks, x GM=2 -> 768 zblk rows
        cheb_mm_v3_kernel<128, 256, 2, 4, 1, 7><<<(P2 * B) / 128, 512, 0, stream>>>(
            h2, t_a, t_b, t_c, Wt3, b3, g3, bt3, zblk);
    }
    // ---- z reduce + head ----
    zred_kernel<<<RSL * 4, 256, 0, stream>>>(zblk, zp2);
    head_kernel<<<B, 512, 0, stream>>>(zp2, mW1, mb1, mW2, mb2, out);

    (void)in_sizes; (void)n_in; (void)out_size; (void)ws_size;
}

// Round 7
// 407.208 us; speedup vs baseline: 5.8324x; 1.0337x over previous
//
#include <hip/hip_runtime.h>
#include <hip/hip_bf16.h>

namespace {

constexpr int B  = 4;
constexpr int P0 = 196608, P1 = 49152, P2 = 12288;
constexpr int DEG = 8;
constexpr float EPS = 1e-5f;
constexpr int NBLK3 = (P2 * B) / 64;   // 768 zblk partial rows
constexpr int RSL = 16;                // zred slices
constexpr int RPB = NBLK3 / RSL;       // 48 zblk rows per slice

typedef __attribute__((ext_vector_type(4))) float f32x4;
typedef __attribute__((ext_vector_type(8))) short s16x8;

__device__ __forceinline__ float b2f(unsigned short u) {
    union { unsigned int i; float f; } c; c.i = (unsigned int)u << 16; return c.f;
}
__device__ __forceinline__ unsigned short f2b(float f) {
    __hip_bfloat16 h = __float2bfloat16(f);   // RNE
    return *reinterpret_cast<unsigned short*>(&h);
}

// ---------------------------------------------------------------------------
// x: (B,P0,16) fp32  ->  xb: (P0,B,16) bf16
// ---------------------------------------------------------------------------
__global__ __launch_bounds__(256)
void x2p_kernel(const float* __restrict__ in, unsigned short* __restrict__ out)
{
    long idx = (long)blockIdx.x * blockDim.x + threadIdx.x;   // P0*B*2 total
    if (idx >= (long)P0 * B * 2) return;
    int  h = (int)(idx & 1);
    int  b = (int)((idx >> 1) & 3);
    long p = idx >> 3;
    const float* src = in + ((size_t)b * P0 + p) * 16 + h * 8;
    float4 v0 = *(const float4*)src;
    float4 v1 = *(const float4*)(src + 4);
    union { uint4 u; unsigned short s[8]; } o;
    o.s[0] = f2b(v0.x); o.s[1] = f2b(v0.y); o.s[2] = f2b(v0.z); o.s[3] = f2b(v0.w);
    o.s[4] = f2b(v1.x); o.s[5] = f2b(v1.y); o.s[6] = f2b(v1.z); o.s[7] = f2b(v1.w);
    *(uint4*)&out[((size_t)p * B + b) * 16 + h * 8] = o.u;
}

// ---------------------------------------------------------------------------
// Weight prep, one launch: W1/W2/W3 -> bf16 transposed; mW1/mW2 -> fp32
// transposed (for contiguous head dot-products).
// ---------------------------------------------------------------------------
__global__ __launch_bounds__(256)
void wt_all_kernel(const float* __restrict__ W1, const float* __restrict__ W2,
                   const float* __restrict__ W3,
                   const float* __restrict__ mW1, const float* __restrict__ mW2,
                   unsigned short* __restrict__ Wt1, unsigned short* __restrict__ Wt2,
                   unsigned short* __restrict__ Wt3,
                   float* __restrict__ mW1t, float* __restrict__ mW2t)
{
    int i = blockIdx.x * 256 + threadIdx.x;
    if (i < 4096) {                       // W1: 64x64
        int n = i % 64, k = i / 64;
        Wt1[n * 64 + k] = f2b(W1[i]);
    } else if (i < 36864) {               // W2: 256x128
        int j = i - 4096;
        int n = j % 128, k = j / 128;
        Wt2[n * 256 + k] = f2b(W2[j]);
    } else if (i < 167936) {              // W3: 512x256
        int j = i - 36864;
        int n = j % 256, k = j / 256;
        Wt3[n * 512 + k] = f2b(W3[j]);
    } else if (i < 299008) {              // mW1: (256,512) -> (512,256) fp32
        int j = i - 167936;
        int n = j % 512, k = j / 512;
        mW1t[(size_t)n * 256 + k] = mW1[j];
    } else if (i < 430080) {              // mW2: (512,256) -> (256,512) fp32
        int j = i - 299008;
        int n = j % 256, k = j / 256;
        mW2t[(size_t)n * 512 + k] = mW2[j];
    }
}

// ---------------------------------------------------------------------------
// Sparse Chebyshev step on (P, B*C) bf16 rows, fp32 accum. Taps staged in LDS.
// ---------------------------------------------------------------------------
template <int CV8>
__global__ __launch_bounds__(256)
void lmul_v2_kernel(const unsigned short* __restrict__ in,
                    const unsigned short* __restrict__ prev,
                    const int* __restrict__ cols, const float* __restrict__ vals,
                    unsigned short* __restrict__ out,
                    float alpha, float beta)
{
    constexpr int ROWS = 256 / CV8;
    __shared__ int   cs[ROWS * DEG];
    __shared__ float vs[ROWS * DEG];
    const int tid = threadIdx.x;
    const long r0 = (long)blockIdx.x * ROWS;
    if (tid < ROWS * DEG) {
        cs[tid] = cols[r0 * DEG + tid];
        vs[tid] = vals[r0 * DEG + tid];
    }
    __syncthreads();

    const int v  = tid & (CV8 - 1);
    const int lr = tid / CV8;
    const uint4* in16 = (const uint4*)in;

    float acc[8] = {0.f,0.f,0.f,0.f,0.f,0.f,0.f,0.f};
#pragma unroll
    for (int d = 0; d < DEG; ++d) {
        int   col = cs[lr * DEG + d];
        float w   = vs[lr * DEG + d];
        union { uint4 u; unsigned short s[8]; } x;
        x.u = in16[(size_t)col * CV8 + v];
#pragma unroll
        for (int j = 0; j < 8; ++j) acc[j] = fmaf(w, b2f(x.s[j]), acc[j]);
    }
    size_t o = (size_t)(r0 + lr) * CV8 + v;
    if (beta != 0.f) {
        union { uint4 u; unsigned short s[8]; } pv;
        pv.u = ((const uint4*)prev)[o];
#pragma unroll
        for (int j = 0; j < 8; ++j)
            acc[j] = fmaf(alpha, acc[j], beta * b2f(pv.s[j]));
    } else if (alpha != 1.f) {
#pragma unroll
        for (int j = 0; j < 8; ++j) acc[j] *= alpha;
    }
    union { uint4 u; unsigned short s[8]; } ou;
#pragma unroll
    for (int j = 0; j < 8; ++j) ou.s[j] = f2b(acc[j]);
    ((uint4*)out)[o] = ou.u;
}

// ---------------------------------------------------------------------------
// Stage-1 fused MM: KC=64, COUT=64, pool 4. W resident in registers,
// A-fragments read directly from global; grid-stride over 16-row wave-tiles.
// ---------------------------------------------------------------------------
__global__ __launch_bounds__(256)
void s1_mm_kernel(const unsigned short* __restrict__ t0,
                  const unsigned short* __restrict__ t1,
                  const unsigned short* __restrict__ t2,
                  const unsigned short* __restrict__ t3,
                  const unsigned short* __restrict__ Wt,
                  const float* __restrict__ bias,
                  const float* __restrict__ gam,
                  const float* __restrict__ bet,
                  unsigned short* __restrict__ out)
{
    const int wave = threadIdx.x >> 6;
    const int lane = threadIdx.x & 63;
    const int g    = lane >> 4;
    const int c16  = lane & 15;

    s16x8 wf[2][4];
#pragma unroll
    for (int ks = 0; ks < 2; ++ks)
#pragma unroll
        for (int n = 0; n < 4; ++n)
            wf[ks][n] = *(const s16x8*)&Wt[(size_t)(n * 16 + c16) * 64 + ks * 32 + g * 8];

    float bz[4], gz[4], tz[4];
#pragma unroll
    for (int n = 0; n < 4; ++n) {
        bz[n] = bias[n * 16 + c16];
        gz[n] = gam [n * 16 + c16];
        tz[n] = bet [n * 16 + c16];
    }

    const unsigned short* tb[4] = { t0, t1, t2, t3 };
    const int term0  = g >> 1;
    const int coloff = (g & 1) * 8;
    const int bb     = c16 >> 2;
    const int px     = c16 & 3;

    constexpr int NT = P0 / 4;
    const int wg     = blockIdx.x * 4 + wave;
    const int wstep  = gridDim.x * 4;

    for (int t = wg; t < NT; t += wstep) {
        size_t rowbase = ((size_t)(t * 4 + px) * 4 + bb) * 16 + coloff;
        s16x8 a0 = *(const s16x8*)&tb[term0    ][rowbase];
        s16x8 a1 = *(const s16x8*)&tb[term0 + 2][rowbase];

        f32x4 acc[4];
#pragma unroll
        for (int n = 0; n < 4; ++n) acc[n] = (f32x4){bz[n], bz[n], bz[n], bz[n]};
#pragma unroll
        for (int n = 0; n < 4; ++n)
            acc[n] = __builtin_amdgcn_mfma_f32_16x16x32_bf16(a0, wf[0][n], acc[n], 0, 0, 0);
#pragma unroll
        for (int n = 0; n < 4; ++n)
            acc[n] = __builtin_amdgcn_mfma_f32_16x16x32_bf16(a1, wf[1][n], acc[n], 0, 0, 0);

        float s[4] = {0,0,0,0}, q[4] = {0,0,0,0};
#pragma unroll
        for (int n = 0; n < 4; ++n)
#pragma unroll
            for (int r = 0; r < 4; ++r) {
                float v = acc[n][r];
                s[r] += v; q[r] += v * v;
            }
#pragma unroll
        for (int msk = 1; msk < 16; msk <<= 1)
#pragma unroll
            for (int r = 0; r < 4; ++r) {
                s[r] += __shfl_xor(s[r], msk, 64);
                q[r] += __shfl_xor(q[r], msk, 64);
            }
        float mu[4], rs[4];
#pragma unroll
        for (int r = 0; r < 4; ++r) {
            mu[r] = s[r] * (1.f / 64.f);
            float var = q[r] * (1.f / 64.f) - mu[r] * mu[r];
            rs[r] = rsqrtf(var + EPS);
        }
        size_t ro = ((size_t)t * 4 + g) * 64;
#pragma unroll
        for (int n = 0; n < 4; ++n) {
            float pv = 0.f;
#pragma unroll
            for (int r = 0; r < 4; ++r) {
                float h = fmaf(gz[n] * rs[r], acc[n][r] - mu[r], tz[n]);
                pv += fmaxf(h, 0.f);
            }
            out[ro + n * 16 + c16] = f2b(pv * 0.25f);
        }
    }
}

// ---------------------------------------------------------------------------
// Stages 2/3 fused MM v3 (unchanged from round 5): 8 waves, 64x64 wave tile,
// T2 XOR-swizzled LDS, cross-wave LN, in-register pool / colsum fusion.
// ---------------------------------------------------------------------------
template <int CIN, int COUT, int GM, int GN, int POOL, int LOG2CIN>
__global__ __launch_bounds__(512)
void cheb_mm_v3_kernel(const unsigned short* __restrict__ t0,
                       const unsigned short* __restrict__ t1,
                       const unsigned short* __restrict__ t2,
                       const unsigned short* __restrict__ t3,
                       const unsigned short* __restrict__ Wt,
                       const float* __restrict__ bias,
                       const float* __restrict__ gam,
                       const float* __restrict__ bet,
                       void* __restrict__ outv)
{
    constexpr int KC   = 4 * CIN;
    constexpr int BM   = GM * 64;
    constexpr int NKCH = KC / 64;

    __shared__ unsigned short As[BM * 64];     // swizzled, 128B/row
    __shared__ unsigned short Ws[COUT * 64];   // swizzled
    __shared__ float sq[BM][GN][2];

    const int tid  = threadIdx.x;
    const int wv   = tid >> 6;
    const int gm   = wv / GN;
    const int gn   = wv % GN;
    const int lane = tid & 63;
    const int g    = lane >> 4;
    const int c16  = lane & 15;

    const unsigned short* tb[4] = { t0, t1, t2, t3 };

    float bz[4], gz[4], tz[4];
#pragma unroll
    for (int n = 0; n < 4; ++n) {
        int col = gn * 64 + n * 16 + c16;
        bz[n] = bias[col]; gz[n] = gam[col]; tz[n] = bet[col];
    }

    f32x4 acc[4][4];
#pragma unroll
    for (int m = 0; m < 4; ++m)
#pragma unroll
        for (int n = 0; n < 4; ++n)
            acc[m][n] = (f32x4){bz[n], bz[n], bz[n], bz[n]};

    for (int kc = 0; kc < NKCH; ++kc) {
        if (kc) __syncthreads();
#pragma unroll
        for (int it = 0; it < BM * 8 / 512; ++it) {
            int i = tid + it * 512;
            int row = i >> 3, v = i & 7;
            int k = kc * 64 + v * 8;
            int term = k >> LOG2CIN;
            int c = k & (CIN - 1);
            size_t srow;
            if constexpr (POOL == 4) {
                int pix = blockIdx.x * (BM / 4) + ((row >> 4) << 2) + (row & 3);
                int rb  = (row >> 2) & 3;
                srow = ((size_t)pix * B + rb) * CIN + c;
            } else {
                srow = ((size_t)(blockIdx.x * BM + row)) * CIN + c;
            }
            *(uint4*)((char*)As + row * 128 + ((v * 16) ^ ((row & 7) << 4))) =
                *(const uint4*)&tb[term][srow];
        }
#pragma unroll
        for (int it = 0; it < COUT * 8 / 512; ++it) {
            int i = tid + it * 512;
            int co = i >> 3, v = i & 7;
            *(uint4*)((char*)Ws + co * 128 + ((v * 16) ^ ((co & 7) << 4))) =
                *(const uint4*)&Wt[(size_t)co * KC + kc * 64 + v * 8];
        }
        __syncthreads();
#pragma unroll
        for (int ks = 0; ks < 2; ++ks) {
            const int cb  = ks * 64 + g * 16;
            const int swz = cb ^ ((c16 & 7) << 4);
            s16x8 a[4], bw[4];
#pragma unroll
            for (int m = 0; m < 4; ++m)
                a[m] = *(const s16x8*)((const char*)As + (gm * 64 + m * 16 + c16) * 128 + swz);
#pragma unroll
            for (int n = 0; n < 4; ++n)
                bw[n] = *(const s16x8*)((const char*)Ws + (gn * 64 + n * 16 + c16) * 128 + swz);
#pragma unroll
            for (int n = 0; n < 4; ++n)
#pragma unroll
                for (int m = 0; m < 4; ++m)
                    acc[m][n] = __builtin_amdgcn_mfma_f32_16x16x32_bf16(a[m], bw[n], acc[m][n], 0, 0, 0);
        }
    }

    float sm[4][4], qm[4][4];
#pragma unroll
    for (int m = 0; m < 4; ++m)
#pragma unroll
        for (int r = 0; r < 4; ++r) { sm[m][r] = 0.f; qm[m][r] = 0.f; }
#pragma unroll
    for (int m = 0; m < 4; ++m)
#pragma unroll
        for (int n = 0; n < 4; ++n)
#pragma unroll
            for (int r = 0; r < 4; ++r) {
                float v = acc[m][n][r];
                sm[m][r] += v; qm[m][r] += v * v;
            }
#pragma unroll
    for (int msk = 1; msk < 16; msk <<= 1)
#pragma unroll
        for (int m = 0; m < 4; ++m)
#pragma unroll
            for (int r = 0; r < 4; ++r) {
                sm[m][r] += __shfl_xor(sm[m][r], msk, 64);
                qm[m][r] += __shfl_xor(qm[m][r], msk, 64);
            }
    __syncthreads();
    if (c16 == 0) {
#pragma unroll
        for (int m = 0; m < 4; ++m)
#pragma unroll
            for (int r = 0; r < 4; ++r) {
                sq[gm * 64 + m * 16 + g * 4 + r][gn][0] = sm[m][r];
                sq[gm * 64 + m * 16 + g * 4 + r][gn][1] = qm[m][r];
            }
    }
    __syncthreads();
    float mu[4][4], rs[4][4];
#pragma unroll
    for (int m = 0; m < 4; ++m)
#pragma unroll
        for (int r = 0; r < 4; ++r) {
            int row = gm * 64 + m * 16 + g * 4 + r;
            float ss = 0.f, qq = 0.f;
#pragma unroll
            for (int j = 0; j < GN; ++j) { ss += sq[row][j][0]; qq += sq[row][j][1]; }
            mu[m][r] = ss * (1.f / COUT);
            float var = qq * (1.f / COUT) - mu[m][r] * mu[m][r];
            rs[m][r] = rsqrtf(var + EPS);
        }

    if constexpr (POOL == 4) {
        unsigned short* outp = (unsigned short*)outv;
#pragma unroll
        for (int m = 0; m < 4; ++m) {
            size_t ro = ((size_t)(blockIdx.x * (BM / 16) + gm * 4 + m) * B + g) * COUT + gn * 64;
#pragma unroll
            for (int n = 0; n < 4; ++n) {
                float pv = 0.f;
#pragma unroll
                for (int r = 0; r < 4; ++r) {
                    float h = fmaf(gz[n] * rs[m][r], acc[m][n][r] - mu[m][r], tz[n]);
                    pv += fmaxf(h, 0.f);
                }
                outp[ro + n * 16 + c16] = f2b(pv * 0.25f);
            }
        }
    } else {
        float part[4][4];   // [n][r]
#pragma unroll
        for (int n = 0; n < 4; ++n)
#pragma unroll
            for (int r = 0; r < 4; ++r) part[n][r] = 0.f;
#pragma unroll
        for (int m = 0; m < 4; ++m)
#pragma unroll
            for (int n = 0; n < 4; ++n)
#pragma unroll
                for (int r = 0; r < 4; ++r) {
                    float h = fmaf(gz[n] * rs[m][r], acc[m][n][r] - mu[m][r], tz[n]);
                    part[n][r] += fmaxf(h, 0.f);
                }
#pragma unroll
        for (int n = 0; n < 4; ++n)
#pragma unroll
            for (int r = 0; r < 4; ++r) {
                part[n][r] += __shfl_xor(part[n][r], 16, 64);
                part[n][r] += __shfl_xor(part[n][r], 32, 64);
            }
        if (g == 0) {
            float* zb = (float*)outv + ((size_t)(blockIdx.x * GM + gm)) * (B * COUT);
#pragma unroll
            for (int n = 0; n < 4; ++n)
#pragma unroll
                for (int r = 0; r < 4; ++r)
                    zb[(size_t)r * COUT + gn * 64 + n * 16 + c16] = part[n][r];
        }
    }
}

// ---------------------------------------------------------------------------
// zblk (768, B*256) -> zp2 (RSL, B*256): coalesced parallel column reduce.
// ---------------------------------------------------------------------------
__global__ __launch_bounds__(256)
void zred_kernel(const float* __restrict__ zblk, float* __restrict__ zp2)
{
    int s   = blockIdx.x >> 2;
    int col = (blockIdx.x & 3) * 256 + threadIdx.x;
    float acc = 0.f;
#pragma unroll 8
    for (int r = 0; r < RPB; ++r)
        acc += zblk[(size_t)(s * RPB + r) * (B * 256) + col];
    zp2[(size_t)s * (B * 256) + col] = acc;
}

// ---------------------------------------------------------------------------
// Head stage A: z = (reduce zp2)/P2 (LDS, per-block redundant);
// hh[b][j] = relu(z[b]·mW1t[j] + mb1[j]).  grid = 16 blocks x 256 thr;
// thread = (jl 0..31, b 0..3, ig 0..1), contiguous float4 weight stream.
// ---------------------------------------------------------------------------
__global__ __launch_bounds__(256)
void headA_kernel(const float* __restrict__ zp2, const float* __restrict__ mW1t,
                  const float* __restrict__ mb1, float* __restrict__ hh)
{
    __shared__ float zs[B * 256];
    __shared__ float ph[256];
    const int tid = threadIdx.x;
    for (int idx = tid; idx < B * 256; idx += 256) {
        float s = 0.f;
#pragma unroll
        for (int sl = 0; sl < RSL; ++sl) s += zp2[(size_t)sl * (B * 256) + idx];
        zs[idx] = s * (1.f / P2);
    }
    __syncthreads();
    const int jl = tid & 31, b = (tid >> 5) & 3, ig = tid >> 7;
    const int j  = blockIdx.x * 32 + jl;
    const float4* wrow = (const float4*)&mW1t[(size_t)j * 256 + ig * 128];
    const float*  zb   = &zs[b * 256 + ig * 128];
    float acc = 0.f;
#pragma unroll
    for (int i4 = 0; i4 < 32; ++i4) {
        float4 wv = wrow[i4];
        acc += zb[i4*4]*wv.x + zb[i4*4+1]*wv.y + zb[i4*4+2]*wv.z + zb[i4*4+3]*wv.w;
    }
    ph[tid] = acc;
    __syncthreads();
    if (tid < 128) {
        float a = ph[tid] + ph[tid + 128] + mb1[j];
        hh[b * 512 + j] = fmaxf(a, 0.f);
    }
}

// ---------------------------------------------------------------------------
// Head stage B: out[b][c] = hh[b]·mW2t[c] + mb2[c]. grid = 8 blocks x 256.
// ---------------------------------------------------------------------------
__global__ __launch_bounds__(256)
void headB_kernel(const float* __restrict__ hh, const float* __restrict__ mW2t,
                  const float* __restrict__ mb2, float* __restrict__ out)
{
    __shared__ float hs[B * 512];
    __shared__ float ph[256];
    const int tid = threadIdx.x;
    for (int idx = tid; idx < B * 512; idx += 256) hs[idx] = hh[idx];
    __syncthreads();
    const int cl = tid & 31, b = (tid >> 5) & 3, ig = tid >> 7;
    const int c  = blockIdx.x * 32 + cl;
    const float4* wrow = (const float4*)&mW2t[(size_t)c * 512 + ig * 256];
    const float*  hb   = &hs[b * 512 + ig * 256];
    float acc = 0.f;
#pragma unroll
    for (int j4 = 0; j4 < 64; ++j4) {
        float4 wv = wrow[j4];
        acc += hb[j4*4]*wv.x + hb[j4*4+1]*wv.y + hb[j4*4+2]*wv.z + hb[j4*4+3]*wv.w;
    }
    ph[tid] = acc;
    __syncthreads();
    if (tid < 128)
        out[b * 256 + c] = ph[tid] + ph[tid + 128] + mb2[c];
}

} // anonymous namespace

extern "C" void kernel_launch(void* const* d_in, const int* in_sizes, int n_in,
                              void* d_out, int out_size, void* d_ws, size_t ws_size,
                              hipStream_t stream)
{
    const float* x     = (const float*)d_in[0];
    const int*   cols1 = (const int*)  d_in[1];
    const float* vals1 = (const float*)d_in[2];
    const int*   cols2 = (const int*)  d_in[3];
    const float* vals2 = (const float*)d_in[4];
    const int*   cols3 = (const int*)  d_in[5];
    const float* vals3 = (const float*)d_in[6];
    const float* W1  = (const float*)d_in[7];
    const float* b1  = (const float*)d_in[8];
    const float* g1  = (const float*)d_in[9];
    const float* bt1 = (const float*)d_in[10];
    const float* W2  = (const float*)d_in[11];
    const float* b2  = (const float*)d_in[12];
    const float* g2  = (const float*)d_in[13];
    const float* bt2 = (const float*)d_in[14];
    const float* W3  = (const float*)d_in[15];
    const float* b3  = (const float*)d_in[16];
    const float* g3  = (const float*)d_in[17];
    const float* bt3 = (const float*)d_in[18];
    const float* mW1 = (const float*)d_in[19];
    const float* mb1 = (const float*)d_in[20];
    const float* mW2 = (const float*)d_in[21];
    const float* mb2 = (const float*)d_in[22];
    float* out = (float*)d_out;

    // ---- workspace layout (256B-aligned slots) ----
    char* w = (char*)d_ws;
    size_t off = 0;
    auto alloc = [&](size_t bytes) -> void* {
        void* p = w + off;
        off += (bytes + 255) & ~(size_t)255;
        return p;
    };
    const size_t E1 = (size_t)B * P0 * 16;
    unsigned short* xb  = (unsigned short*)alloc(E1 * 2);        // (P0,B,16)
    unsigned short* t_a = (unsigned short*)alloc(E1 * 2);
    unsigned short* t_b = (unsigned short*)alloc(E1 * 2);
    unsigned short* t_c = (unsigned short*)alloc(E1 * 2);
    unsigned short* h1  = (unsigned short*)alloc((size_t)P1 * B * 64 * 2);
    unsigned short* h2  = (unsigned short*)alloc((size_t)P2 * B * 128 * 2);
    unsigned short* Wt1 = (unsigned short*)alloc(64 * 64 * 2);
    unsigned short* Wt2 = (unsigned short*)alloc(256 * 128 * 2);
    unsigned short* Wt3 = (unsigned short*)alloc(512 * 256 * 2);
    float*          mW1t = (float*)alloc((size_t)512 * 256 * 4);
    float*          mW2t = (float*)alloc((size_t)256 * 512 * 4);
    float*          zblk = (float*)alloc((size_t)NBLK3 * B * 256 * 4);
    float*          zp2  = (float*)alloc((size_t)RSL * B * 256 * 4);
    float*          hh   = (float*)alloc((size_t)B * 512 * 4);

    // ---- precompute: layout transpose + weight prep ----
    x2p_kernel<<<(int)(((long)P0 * B * 2 + 255) / 256), 256, 0, stream>>>(x, xb);
    wt_all_kernel<<<(430080 + 255) / 256, 256, 0, stream>>>(
        W1, W2, W3, mW1, mW2, Wt1, Wt2, Wt3, mW1t, mW2t);

    // ---- Stage 1: P0, 16 -> 64, pool 4 ----
    {
        lmul_v2_kernel<8><<<P0 / 32, 256, 0, stream>>>(xb,  nullptr, cols1, vals1, t_a, 1.f,  0.f);
        lmul_v2_kernel<8><<<P0 / 32, 256, 0, stream>>>(t_a, xb,      cols1, vals1, t_b, 2.f, -1.f);
        lmul_v2_kernel<8><<<P0 / 32, 256, 0, stream>>>(t_b, t_a,     cols1, vals1, t_c, 2.f, -1.f);
        s1_mm_kernel<<<2048, 256, 0, stream>>>(xb, t_a, t_b, t_c, Wt1, b1, g1, bt1, h1);
    }
    // ---- Stage 2: P1, 64 -> 128, pool 4 ----
    {
        lmul_v2_kernel<32><<<P1 / 8, 256, 0, stream>>>(h1,  nullptr, cols2, vals2, t_a, 1.f,  0.f);
        lmul_v2_kernel<32><<<P1 / 8, 256, 0, stream>>>(t_a, h1,      cols2, vals2, t_b, 2.f, -1.f);
        lmul_v2_kernel<32><<<P1 / 8, 256, 0, stream>>>(t_b, t_a,     cols2, vals2, t_c, 2.f, -1.f);
        cheb_mm_v3_kernel<64, 128, 4, 2, 4, 6><<<(P1 * B) / 256, 512, 0, stream>>>(
            h1, t_a, t_b, t_c, Wt2, b2, g2, bt2, h2);
    }
    // ---- Stage 3: P2, 128 -> 256, no pool; emits colsum partials ----
    {
        lmul_v2_kernel<64><<<P2 / 4, 256, 0, stream>>>(h2,  nullptr, cols3, vals3, t_a, 1.f,  0.f);
        lmul_v2_kernel<64><<<P2 / 4, 256, 0, stream>>>(t_a, h2,      cols3, vals3, t_b, 2.f, -1.f);
        lmul_v2_kernel<64><<<P2 / 4, 256, 0, stream>>>(t_b, t_a,     cols3, vals3, t_c, 2.f, -1.f);
        cheb_mm_v3_kernel<128, 256, 2, 4, 1, 7><<<(P2 * B) / 128, 512, 0, stream>>>(
            h2, t_a, t_b, t_c, Wt3, b3, g3, bt3, zblk);
    }
    // ---- z reduce + head ----
    zred_kernel<<<RSL * 4, 256, 0, stream>>>(zblk, zp2);
    headA_kernel<<<16, 256, 0, stream>>>(zp2, mW1t, mb1, hh);
    headB_kernel<<<8, 256, 0, stream>>>(hh, mW2t, mb2, out);

    (void)in_sizes; (void)n_in; (void)out_size; (void)ws_size;
}